// Round 1
// baseline (6902.821 us; speedup 1.0000x reference)
//
#include <hip/hip_runtime.h>

typedef unsigned short u16;
typedef unsigned int u32;
typedef __attribute__((ext_vector_type(4))) float f32x4;
typedef __attribute__((ext_vector_type(8))) __bf16 bf16x8;

__device__ __forceinline__ u16 f2bf(float f) {
    u32 u = __builtin_bit_cast(u32, f);
    u += 0x7fffu + ((u >> 16) & 1u);
    return (u16)(u >> 16);
}

// ---------------- elementwise conversion ----------------
__global__ __launch_bounds__(256) void cvt_bf16_kernel(const float4* __restrict__ in,
                                                       ushort4* __restrict__ out, int n4) {
    int i = blockIdx.x * 256 + threadIdx.x;
    if (i < n4) {
        float4 v = in[i];
        ushort4 o;
        o.x = f2bf(v.x); o.y = f2bf(v.y); o.z = f2bf(v.z); o.w = f2bf(v.w);
        out[i] = o;
    }
}

// transpose + convert: W [B][K][N] f32 -> Wt [B][N][K] bf16
__global__ __launch_bounds__(256) void transcvt_kernel(const float* __restrict__ W,
                                                       u16* __restrict__ Wt, int K, int N) {
    __shared__ u16 t[32][33];
    int b = blockIdx.z;
    const float* Wb = W + (size_t)b * K * N;
    u16* Wtb = Wt + (size_t)b * K * N;
    int n0 = blockIdx.x * 32, k0 = blockIdx.y * 32;
    int tx = threadIdx.x, ty = threadIdx.y;
#pragma unroll
    for (int j = 0; j < 4; ++j)
        t[ty + j * 8][tx] = f2bf(Wb[(size_t)(k0 + ty + j * 8) * N + n0 + tx]);
    __syncthreads();
#pragma unroll
    for (int j = 0; j < 4; ++j)
        Wtb[(size_t)(n0 + ty + j * 8) * K + k0 + tx] = t[tx][ty + j * 8];
}

// ---------------- row softmax: S [M][N] f32 -> P [M][N] bf16 ----------------
__global__ __launch_bounds__(256) void softmax_kernel(const float* __restrict__ S,
                                                      u16* __restrict__ P, int N) {
    int row = blockIdx.x;
    const float* s = S + (size_t)row * N;
    u16* p = P + (size_t)row * N;
    int tid = threadIdx.x, lane = tid & 63, wid = tid >> 6;
    int cnt = N >> 8;                 // N in {2048,4096} -> 8 or 16
    __shared__ float red[4];
    __shared__ float bcast[2];
    float mx = -3.0e38f;
    for (int i = 0; i < cnt; ++i) mx = fmaxf(mx, s[i * 256 + tid]);
#pragma unroll
    for (int off = 32; off; off >>= 1) mx = fmaxf(mx, __shfl_down(mx, off));
    if (lane == 0) red[wid] = mx;
    __syncthreads();
    if (tid == 0) bcast[0] = fmaxf(fmaxf(red[0], red[1]), fmaxf(red[2], red[3]));
    __syncthreads();
    mx = bcast[0];
    float ev[16];
    float sum = 0.f;
    for (int i = 0; i < cnt; ++i) {
        float e = __expf(s[i * 256 + tid] - mx);
        ev[i] = e;
        sum += e;
    }
#pragma unroll
    for (int off = 32; off; off >>= 1) sum += __shfl_down(sum, off);
    if (lane == 0) red[wid] = sum;
    __syncthreads();
    if (tid == 0) bcast[1] = red[0] + red[1] + red[2] + red[3];
    __syncthreads();
    float rinv = 1.f / bcast[1];
    for (int i = 0; i < cnt; ++i) p[i * 256 + tid] = f2bf(ev[i] * rinv);
}

// ---------------- GEMM: C = A (M,K) * B^T (N,K) ----------------
// Raw-layout semantics: lda/ldb are ROW STRIDES of the raw arrays.
//   TA=0: A_logical[m,k] = A[m*lda + k];   TA=1: A_logical[m,k] = A[k*lda + m]
//   TB=0: B_logical[n,k] = B[n*ldb + k];   TB=1: B_logical[n,k] = B[k*ldb + n]
enum { E_PROJ = 0, E_SC, E_SCM, E_ELW, E_ELA };

template <int EPI, int TA, int TB>
__global__ __launch_bounds__(256) void gemm_nt(const u16* __restrict__ A, const u16* __restrict__ B,
                                               void* __restrict__ Cv, const float* __restrict__ bias,
                                               int M, int N, int K, int lda, int ldb, int ldc,
                                               float scale) {
    __shared__ __align__(16) u16 As[128][40];
    __shared__ __align__(16) u16 Bs[128][40];
    const int tid = threadIdx.x;
    const int lane = tid & 63;
    const int wid = tid >> 6;
    const int wr = (wid >> 1) << 6;       // 2x2 waves, each 64x64
    const int wc = (wid & 1) << 6;
    const int row0 = blockIdx.x << 7;
    const int col0 = blockIdx.y << 7;
    f32x4 acc[4][4] = {};

    for (int k0 = 0; k0 < K; k0 += 32) {
        __syncthreads();
        // ---- stage A tile [128 rows][32 k] ----
        if (!TA) {
#pragma unroll
            for (int i = 0; i < 2; ++i) {
                int c = tid + (i << 8);
                int r = c >> 2, sg = (c & 3) << 3;
                *reinterpret_cast<uint4*>(&As[r][sg]) =
                    *reinterpret_cast<const uint4*>(A + (size_t)(row0 + r) * lda + k0 + sg);
            }
        } else {
#pragma unroll
            for (int i = 0; i < 2; ++i) {
                int c = tid + (i << 8);
                int kk = c >> 4, ms = (c & 15) << 3;
                uint4 v = *reinterpret_cast<const uint4*>(A + (size_t)(k0 + kk) * lda + row0 + ms);
                const u16* pv = reinterpret_cast<const u16*>(&v);
#pragma unroll
                for (int j = 0; j < 8; ++j) As[ms + j][kk] = pv[j];
            }
        }
        // ---- stage B tile [128 cols][32 k] ----
        if (!TB) {
#pragma unroll
            for (int i = 0; i < 2; ++i) {
                int c = tid + (i << 8);
                int r = c >> 2, sg = (c & 3) << 3;
                *reinterpret_cast<uint4*>(&Bs[r][sg]) =
                    *reinterpret_cast<const uint4*>(B + (size_t)(col0 + r) * ldb + k0 + sg);
            }
        } else {
#pragma unroll
            for (int i = 0; i < 2; ++i) {
                int c = tid + (i << 8);
                int kk = c >> 4, ns = (c & 15) << 3;
                uint4 v = *reinterpret_cast<const uint4*>(B + (size_t)(k0 + kk) * ldb + col0 + ns);
                const u16* pv = reinterpret_cast<const u16*>(&v);
#pragma unroll
                for (int j = 0; j < 8; ++j) Bs[ns + j][kk] = pv[j];
            }
        }
        __syncthreads();
        bf16x8 af[4], bv[4];
#pragma unroll
        for (int m = 0; m < 4; ++m)
            af[m] = *reinterpret_cast<const bf16x8*>(&As[wr + m * 16 + (lane & 15)][(lane >> 4) << 3]);
#pragma unroll
        for (int n = 0; n < 4; ++n)
            bv[n] = *reinterpret_cast<const bf16x8*>(&Bs[wc + n * 16 + (lane & 15)][(lane >> 4) << 3]);
#pragma unroll
        for (int m = 0; m < 4; ++m)
#pragma unroll
            for (int n = 0; n < 4; ++n)
                acc[m][n] = __builtin_amdgcn_mfma_f32_16x16x32_bf16(af[m], bv[n], acc[m][n], 0, 0, 0);
    }

#pragma unroll
    for (int m = 0; m < 4; ++m) {
#pragma unroll
        for (int n = 0; n < 4; ++n) {
#pragma unroll
            for (int j = 0; j < 4; ++j) {
                int row = row0 + wr + m * 16 + ((lane >> 4) << 2) + j;
                int col = col0 + wc + n * 16 + (lane & 15);
                float v = acc[m][n][j];
                if (EPI == E_PROJ) {
                    v += bias[col];
                    reinterpret_cast<u16*>(Cv)[(size_t)row * ldc + col] = f2bf(v);
                } else if (EPI == E_SC || EPI == E_SCM) {
                    v *= scale;
                    if (EPI == E_SCM && row == col) v = -1e9f;
                    reinterpret_cast<float*>(Cv)[(size_t)row * ldc + col] = v;
                } else {
                    v = v > 0.f ? v : (__expf(v) - 1.f);
                    float* cp = reinterpret_cast<float*>(Cv) + (size_t)row * ldc + col;
                    if (EPI == E_ELA) *cp += v;
                    else *cp = v;
                }
            }
        }
    }
}

// ---------------- combines ----------------
__global__ __launch_bounds__(256) void combine_obj_kernel(const float* __restrict__ feat,
        const float* __restrict__ a, const float* __restrict__ b,
        const float* __restrict__ c, const float* __restrict__ d,
        float* __restrict__ out, u16* __restrict__ outbf) {
    int i = blockIdx.x * 256 + threadIdx.x;
    int r = i >> 10, col = i & 1023;
    size_t half = (size_t)r * 512 + (col & 511);
    float t1 = (col < 512) ? a[half] : b[half];
    float t2 = (col < 512) ? c[half] : d[half];
    float o = (feat[i] + t1 + t2) * (1.f / 3.f);
    out[i] = o;
    outbf[i] = f2bf(o);
}

__global__ __launch_bounds__(256) void combine_rel1_kernel(const float* __restrict__ feat,
        const float* __restrict__ a, const float* __restrict__ b, u16* __restrict__ outbf) {
    int i = blockIdx.x * 256 + threadIdx.x;
    int r = i >> 10, col = i & 1023;
    size_t half = (size_t)r * 512 + (col & 511);
    float t = (col < 512) ? a[half] : b[half];
    outbf[i] = f2bf((feat[i] + t) * 0.5f);
}

__global__ __launch_bounds__(256) void combine_rel2_kernel(const float* __restrict__ feat,
        const float* __restrict__ a, const float* __restrict__ b, float* __restrict__ out) {
    int i = blockIdx.x * 256 + threadIdx.x;
    int r = i >> 10, col = i & 1023;
    size_t half = (size_t)r * 512 + (col & 511);
    float t = (col < 512) ? a[half] : b[half];
    out[i] = (feat[i] + t) * 0.5f;
}

// ---------------- dispatch helper ----------------
static void G(int epi, int ta, int tb, const u16* A, const u16* B, void* C, const float* bias,
              int M, int N, int K, int lda, int ldb, int ldc, float scale, hipStream_t st) {
    dim3 g(M / 128, N / 128);
    (void)tb;
    if (epi == E_PROJ)
        gemm_nt<E_PROJ, 0, 0><<<g, 256, 0, st>>>(A, B, C, bias, M, N, K, lda, ldb, ldc, scale);
    else if (epi == E_SC)
        gemm_nt<E_SC, 0, 0><<<g, 256, 0, st>>>(A, B, C, bias, M, N, K, lda, ldb, ldc, scale);
    else if (epi == E_SCM)
        gemm_nt<E_SCM, 0, 0><<<g, 256, 0, st>>>(A, B, C, bias, M, N, K, lda, ldb, ldc, scale);
    else if (epi == E_ELW && ta == 0)
        gemm_nt<E_ELW, 0, 1><<<g, 256, 0, st>>>(A, B, C, bias, M, N, K, lda, ldb, ldc, scale);
    else if (epi == E_ELW)
        gemm_nt<E_ELW, 1, 1><<<g, 256, 0, st>>>(A, B, C, bias, M, N, K, lda, ldb, ldc, scale);
    else if (epi == E_ELA && ta == 0)
        gemm_nt<E_ELA, 0, 1><<<g, 256, 0, st>>>(A, B, C, bias, M, N, K, lda, ldb, ldc, scale);
    else
        gemm_nt<E_ELA, 1, 1><<<g, 256, 0, st>>>(A, B, C, bias, M, N, K, lda, ldb, ldc, scale);
}

extern "C" void kernel_launch(void* const* d_in, const int* in_sizes, int n_in,
                              void* d_out, int out_size, void* d_ws, size_t ws_size,
                              hipStream_t stream) {
    (void)in_sizes; (void)n_in; (void)out_size; (void)ws_size;
    const float* feat_obj = (const float*)d_in[0];
    const float* feat_rel = (const float*)d_in[1];
    const float* W_cat = (const float*)d_in[2];
    const float* b_cat = (const float*)d_in[3];
    const float* W_out = (const float*)d_in[4];
    const float* b_out = (const float*)d_in[5];
    float* out_obj = (float*)d_out;
    float* out_rel = (float*)d_out + (size_t)2048 * 1024;

    char* w = (char*)d_ws;
    auto alloc = [&](size_t bytes) { void* p = (void*)w; w += (bytes + 255) & ~(size_t)255; return p; };
    u16* bf_obj  = (u16*)alloc((size_t)2048 * 1024 * 2);
    u16* bf_rel  = (u16*)alloc((size_t)4096 * 1024 * 2);
    u16* bf_obj2 = (u16*)alloc((size_t)2048 * 1024 * 2);
    u16* bf_rel2 = (u16*)alloc((size_t)4096 * 1024 * 2);
    u16* Wt_cat  = (u16*)alloc((size_t)12 * 512 * 1024 * 2);
    u16* Wt_out  = (u16*)alloc((size_t)8 * 3072 * 1024 * 2);
    u16* bufQ    = (u16*)alloc((size_t)4096 * 3072 * 2);
    u16* bufK    = (u16*)alloc((size_t)4096 * 3072 * 2);
    u16* bufVq   = (u16*)alloc((size_t)4096 * 3072 * 2);
    u16* bufVk   = (u16*)alloc((size_t)4096 * 512 * 2);
    float* Sbuf  = (float*)alloc((size_t)2048 * 4096 * 4);
    u16* Pbuf    = (u16*)alloc((size_t)2048 * 4096 * 2);
    float* sub_obj  = (float*)alloc((size_t)2048 * 512 * 4);
    float* obj_sub  = (float*)alloc((size_t)2048 * 512 * 4);
    float* sub_rel  = (float*)alloc((size_t)2048 * 512 * 4);
    float* obj_rel  = (float*)alloc((size_t)2048 * 512 * 4);
    float* rel_obj  = (float*)alloc((size_t)4096 * 512 * 4);
    float* rel_sub  = (float*)alloc((size_t)4096 * 512 * 4);
    float* rel_obj2 = (float*)alloc((size_t)4096 * 512 * 4);
    float* rel_sub2 = (float*)alloc((size_t)4096 * 512 * 4);

    // conversions
    cvt_bf16_kernel<<<2048, 256, 0, stream>>>((const float4*)feat_obj, (ushort4*)bf_obj, 2048 * 1024 / 4);
    cvt_bf16_kernel<<<4096, 256, 0, stream>>>((const float4*)feat_rel, (ushort4*)bf_rel, 4096 * 1024 / 4);
    transcvt_kernel<<<dim3(512 / 32, 1024 / 32, 12), dim3(32, 8), 0, stream>>>(W_cat, Wt_cat, 1024, 512);
    transcvt_kernel<<<dim3(3072 / 32, 1024 / 32, 8), dim3(32, 8), 0, stream>>>(W_out, Wt_out, 1024, 3072);

    const float sc1 = 0.08838834764831845f;  // 1/sqrt(128)
    const float sc2 = 0.04419417382415922f;  // 1/sqrt(512)

    // ---------------- stage 1: three concat=True MHAs, h=4, d_k=128 ----------------
    struct MhaCfg { const u16* xq; const u16* xk; int Nq, Nk; float* d1; float* d2; int mask; };
    MhaCfg cfg[3] = {
        { bf_obj, bf_obj, 2048, 2048, sub_obj, obj_sub, 1 },
        { bf_obj, bf_rel, 2048, 4096, sub_rel, rel_sub, 0 },
        { bf_rel, bf_obj, 4096, 2048, rel_obj, obj_rel, 0 },
    };
    for (int m = 0; m < 3; ++m) {
        const u16* Wt = Wt_cat + (size_t)m * 4 * 512 * 1024;
        const float* bb = b_cat + m * 4 * 512;
        int Nq = cfg[m].Nq, Nk = cfg[m].Nk;
        G(E_PROJ, 0, 0, cfg[m].xq, Wt + (size_t)0 * 512 * 1024, bufQ,  bb + 0,    Nq, 512, 1024, 1024, 1024, 512, 0.f, stream);
        G(E_PROJ, 0, 0, cfg[m].xk, Wt + (size_t)1 * 512 * 1024, bufK,  bb + 512,  Nk, 512, 1024, 1024, 1024, 512, 0.f, stream);
        G(E_PROJ, 0, 0, cfg[m].xq, Wt + (size_t)2 * 512 * 1024, bufVq, bb + 1024, Nq, 512, 1024, 1024, 1024, 512, 0.f, stream);
        G(E_PROJ, 0, 0, cfg[m].xk, Wt + (size_t)3 * 512 * 1024, bufVk, bb + 1536, Nk, 512, 1024, 1024, 1024, 512, 0.f, stream);
        for (int h = 0; h < 4; ++h) {
            G(cfg[m].mask ? E_SCM : E_SC, 0, 0, bufQ + h * 128, bufK + h * 128, Sbuf, nullptr,
              Nq, Nk, 128, 512, 512, Nk, sc1, stream);
            softmax_kernel<<<Nq, 256, 0, stream>>>(Sbuf, Pbuf, Nk);
            // a1 = elu(P @ kv_h): M=Nq, N=128, K=Nk
            G(E_ELW, 0, 1, Pbuf, bufVk + h * 128, cfg[m].d1 + h * 128, nullptr,
              Nq, 128, Nk, Nk, 512, 512, 0.f, stream);
            // a2 = elu(P^T @ qv_h): M=Nk, N=128, K=Nq
            G(E_ELW, 1, 1, Pbuf, bufVq + h * 128, cfg[m].d2 + h * 128, nullptr,
              Nk, 128, Nq, Nk, 512, 512, 0.f, stream);
        }
    }

    combine_obj_kernel<<<8192, 256, 0, stream>>>(feat_obj, sub_obj, obj_sub, sub_rel, obj_rel, out_obj, bf_obj2);
    combine_rel1_kernel<<<16384, 256, 0, stream>>>(feat_rel, rel_obj, rel_sub, bf_rel2);

    // ---------------- stage 2: two concat=False MHAs, h=6, d_k=512 ----------------
    // mha0: xq=obj2 (2048), xk=rel2 (4096); need a2 only -> q, k, qv
    {
        const u16* Wt = Wt_out;
        const float* bb = b_out;
        G(E_PROJ, 0, 0, bf_obj2, Wt + (size_t)0 * 3072 * 1024, bufQ,  bb + 0 * 3072, 2048, 3072, 1024, 1024, 1024, 3072, 0.f, stream);
        G(E_PROJ, 0, 0, bf_rel2, Wt + (size_t)1 * 3072 * 1024, bufK,  bb + 1 * 3072, 4096, 3072, 1024, 1024, 1024, 3072, 0.f, stream);
        G(E_PROJ, 0, 0, bf_obj2, Wt + (size_t)2 * 3072 * 1024, bufVq, bb + 2 * 3072, 2048, 3072, 1024, 1024, 1024, 3072, 0.f, stream);
        for (int h = 0; h < 6; ++h) {
            G(E_SC, 0, 0, bufQ + h * 512, bufK + h * 512, Sbuf, nullptr,
              2048, 4096, 512, 3072, 3072, 4096, sc2, stream);
            softmax_kernel<<<2048, 256, 0, stream>>>(Sbuf, Pbuf, 4096);
            // a2_h = elu(P^T @ qv_h), accumulate over heads: M=4096, N=512, K=2048
            G(h ? E_ELA : E_ELW, 1, 1, Pbuf, bufVq + h * 512, rel_sub2, nullptr,
              4096, 512, 2048, 4096, 3072, 512, 0.f, stream);
        }
    }
    // mha1: xq=rel2 (4096), xk=obj2 (2048); need a1 only -> q, k, kv
    {
        const u16* Wt = Wt_out + (size_t)4 * 3072 * 1024;
        const float* bb = b_out + 4 * 3072;
        G(E_PROJ, 0, 0, bf_rel2, Wt + (size_t)0 * 3072 * 1024, bufQ,  bb + 0 * 3072, 4096, 3072, 1024, 1024, 1024, 3072, 0.f, stream);
        G(E_PROJ, 0, 0, bf_obj2, Wt + (size_t)1 * 3072 * 1024, bufK,  bb + 1 * 3072, 2048, 3072, 1024, 1024, 1024, 3072, 0.f, stream);
        G(E_PROJ, 0, 0, bf_obj2, Wt + (size_t)3 * 3072 * 1024, bufVq, bb + 3 * 3072, 2048, 3072, 1024, 1024, 1024, 3072, 0.f, stream);
        for (int h = 0; h < 6; ++h) {
            G(E_SC, 0, 0, bufQ + h * 512, bufK + h * 512, Sbuf, nullptr,
              4096, 2048, 512, 3072, 3072, 2048, sc2, stream);
            softmax_kernel<<<4096, 256, 0, stream>>>(Sbuf, Pbuf, 2048);
            // a1_h = elu(P @ kv_h), accumulate over heads: M=4096, N=512, K=2048
            G(h ? E_ELA : E_ELW, 0, 1, Pbuf, bufVq + h * 512, rel_obj2, nullptr,
              4096, 512, 2048, 2048, 3072, 512, 0.f, stream);
        }
    }

    combine_rel2_kernel<<<16384, 256, 0, stream>>>(feat_rel, rel_obj2, rel_sub2, out_rel);
}

// Round 2
// 2026.443 us; speedup vs baseline: 3.4064x; 3.4064x over previous
//
#include <hip/hip_runtime.h>

typedef unsigned short u16;
typedef unsigned int u32;
typedef __attribute__((ext_vector_type(4))) float f32x4;
typedef __attribute__((ext_vector_type(8))) __bf16 bf16x8;

#if defined(__has_builtin)
#if __has_builtin(__builtin_amdgcn_global_load_lds)
#define HAS_GLL 1
#endif
#endif

__device__ __forceinline__ u16 f2bf(float f) {
    u32 u = __builtin_bit_cast(u32, f);
    u += 0x7fffu + ((u >> 16) & 1u);
    return (u16)(u >> 16);
}

// ---------------- elementwise conversion ----------------
__global__ __launch_bounds__(256) void cvt_bf16_kernel(const float4* __restrict__ in,
                                                       ushort4* __restrict__ out, int n4) {
    int i = blockIdx.x * 256 + threadIdx.x;
    if (i < n4) {
        float4 v = in[i];
        ushort4 o;
        o.x = f2bf(v.x); o.y = f2bf(v.y); o.z = f2bf(v.z); o.w = f2bf(v.w);
        out[i] = o;
    }
}

// transpose + convert: W [B][K][N] f32 -> Wt [B][N][K] bf16
__global__ __launch_bounds__(256) void transcvt_kernel(const float* __restrict__ W,
                                                       u16* __restrict__ Wt, int K, int N) {
    __shared__ u16 t[32][33];
    int b = blockIdx.z;
    const float* Wb = W + (size_t)b * K * N;
    u16* Wtb = Wt + (size_t)b * K * N;
    int n0 = blockIdx.x * 32, k0 = blockIdx.y * 32;
    int tx = threadIdx.x, ty = threadIdx.y;
#pragma unroll
    for (int j = 0; j < 4; ++j)
        t[ty + j * 8][tx] = f2bf(Wb[(size_t)(k0 + ty + j * 8) * N + n0 + tx]);
    __syncthreads();
#pragma unroll
    for (int j = 0; j < 4; ++j)
        Wtb[(size_t)(n0 + ty + j * 8) * K + k0 + tx] = t[tx][ty + j * 8];
}

// bf16 transpose: in [R][C] -> out [C][R]; R,C multiples of 64
__global__ __launch_bounds__(256) void transpose_bf16_kernel(const u16* __restrict__ in,
                                                             u16* __restrict__ out, int R, int C) {
    __shared__ u16 t[64][65];
    int r0 = blockIdx.x * 64, c0 = blockIdx.y * 64;
    int tx = threadIdx.x & 15, ty = threadIdx.x >> 4;
#pragma unroll
    for (int j = 0; j < 4; ++j) {
        int r = ty + j * 16;
        ushort4 v = *reinterpret_cast<const ushort4*>(in + (size_t)(r0 + r) * C + c0 + tx * 4);
        t[r][tx * 4 + 0] = v.x; t[r][tx * 4 + 1] = v.y;
        t[r][tx * 4 + 2] = v.z; t[r][tx * 4 + 3] = v.w;
    }
    __syncthreads();
#pragma unroll
    for (int j = 0; j < 4; ++j) {
        int c = ty + j * 16;
        ushort4 v;
        v.x = t[tx * 4 + 0][c]; v.y = t[tx * 4 + 1][c];
        v.z = t[tx * 4 + 2][c]; v.w = t[tx * 4 + 3][c];
        *reinterpret_cast<ushort4*>(out + (size_t)(c0 + c) * R + r0 + tx * 4) = v;
    }
}

// ---------------- row softmax: S [M][N] f32 -> P [M][N] bf16 ----------------
__global__ __launch_bounds__(256) void softmax_kernel(const float* __restrict__ S,
                                                      u16* __restrict__ P, int N) {
    int row = blockIdx.x;
    const float* s = S + (size_t)row * N;
    u16* p = P + (size_t)row * N;
    int tid = threadIdx.x, lane = tid & 63, wid = tid >> 6;
    int cnt = N >> 8;                 // N in {2048,4096} -> 8 or 16
    __shared__ float red[4];
    __shared__ float bcast[2];
    float mx = -3.0e38f;
    for (int i = 0; i < cnt; ++i) mx = fmaxf(mx, s[i * 256 + tid]);
#pragma unroll
    for (int off = 32; off; off >>= 1) mx = fmaxf(mx, __shfl_down(mx, off));
    if (lane == 0) red[wid] = mx;
    __syncthreads();
    if (tid == 0) bcast[0] = fmaxf(fmaxf(red[0], red[1]), fmaxf(red[2], red[3]));
    __syncthreads();
    mx = bcast[0];
    float ev[16];
    float sum = 0.f;
    for (int i = 0; i < cnt; ++i) {
        float e = __expf(s[i * 256 + tid] - mx);
        ev[i] = e;
        sum += e;
    }
#pragma unroll
    for (int off = 32; off; off >>= 1) sum += __shfl_down(sum, off);
    if (lane == 0) red[wid] = sum;
    __syncthreads();
    if (tid == 0) bcast[1] = red[0] + red[1] + red[2] + red[3];
    __syncthreads();
    float rinv = 1.f / bcast[1];
    for (int i = 0; i < cnt; ++i) p[i * 256 + tid] = f2bf(ev[i] * rinv);
}

// ---------------- GEMM: C = A (M,K) * B^T (N,K), all row-major fast path ----------------
// LDS: linear [BM][32] u16, XOR-swizzled k-chunks: physical chunk = logical ^ ((row>>1)&3).
// Staged via global_load_lds width 16 (pre-swizzled global source), read via swizzled ds_read_b128.
enum { E_PROJ = 0, E_SC, E_SCM, E_PART };

template <int EPI, int BM>
__global__ __launch_bounds__(256) void gemm_nt(const u16* __restrict__ A, const u16* __restrict__ B,
                                               void* __restrict__ Cv, const float* __restrict__ bias,
                                               int M, int N, int K, int lda, int ldb, int ldc,
                                               float scale, long sAz, long sBz, long sCz) {
    constexpr int MF = BM / 32;               // 16x16 frags per wave dim: 4 (BM=128) or 2 (BM=64)
    constexpr int ITERS = BM * 32 / (256 * 8);
    __shared__ __align__(16) u16 As[BM * 32];
    __shared__ __align__(16) u16 Bs[BM * 32];
    const int tid = threadIdx.x;
    const int lane = tid & 63;
    const int wid = tid >> 6;
    const int wr = (wid >> 1) * (BM / 2);
    const int wc = (wid & 1) * (BM / 2);
    const int row0 = blockIdx.x * BM;
    const int col0 = blockIdx.y * BM;
    const long zo = blockIdx.z;
    const u16* Az = A + zo * sAz;
    const u16* Bz = B + zo * sBz;
    f32x4 acc[MF][MF] = {};

    for (int k0 = 0; k0 < K; k0 += 32) {
        __syncthreads();
#pragma unroll
        for (int i = 0; i < ITERS; ++i) {
            int c = tid + i * 256;
            int r = c >> 2;
            int lch = (c & 3) ^ ((r >> 1) & 3);   // logical k-chunk held by this physical slot
            const u16* sa = Az + (size_t)(row0 + r) * lda + k0 + lch * 8;
            const u16* sb = Bz + (size_t)(col0 + r) * ldb + k0 + lch * 8;
#ifdef HAS_GLL
            __builtin_amdgcn_global_load_lds(
                (const __attribute__((address_space(1))) void*)sa,
                (__attribute__((address_space(3))) void*)(&As[c * 8]), 16, 0, 0);
            __builtin_amdgcn_global_load_lds(
                (const __attribute__((address_space(1))) void*)sb,
                (__attribute__((address_space(3))) void*)(&Bs[c * 8]), 16, 0, 0);
#else
            *reinterpret_cast<uint4*>(&As[c * 8]) = *reinterpret_cast<const uint4*>(sa);
            *reinterpret_cast<uint4*>(&Bs[c * 8]) = *reinterpret_cast<const uint4*>(sb);
#endif
        }
        __syncthreads();
        bf16x8 af[MF], bv[MF];
#pragma unroll
        for (int m = 0; m < MF; ++m) {
            int rr = wr + m * 16 + (lane & 15);
            int p = (lane >> 4) ^ ((rr >> 1) & 3);
            af[m] = *reinterpret_cast<const bf16x8*>(&As[rr * 32 + p * 8]);
        }
#pragma unroll
        for (int n = 0; n < MF; ++n) {
            int rr = wc + n * 16 + (lane & 15);
            int p = (lane >> 4) ^ ((rr >> 1) & 3);
            bv[n] = *reinterpret_cast<const bf16x8*>(&Bs[rr * 32 + p * 8]);
        }
#pragma unroll
        for (int m = 0; m < MF; ++m)
#pragma unroll
            for (int n = 0; n < MF; ++n)
                acc[m][n] = __builtin_amdgcn_mfma_f32_16x16x32_bf16(af[m], bv[n], acc[m][n], 0, 0, 0);
    }

#pragma unroll
    for (int m = 0; m < MF; ++m) {
#pragma unroll
        for (int n = 0; n < MF; ++n) {
#pragma unroll
            for (int j = 0; j < 4; ++j) {
                int row = row0 + wr + m * 16 + ((lane >> 4) << 2) + j;
                int col = col0 + wc + n * 16 + (lane & 15);
                float v = acc[m][n][j];
                if (EPI == E_PROJ) {
                    v += bias[col];
                    reinterpret_cast<u16*>(Cv)[(size_t)row * ldc + col] = f2bf(v);
                } else if (EPI == E_SC || EPI == E_SCM) {
                    v *= scale;
                    if (EPI == E_SCM && row == col) v = -1e9f;
                    reinterpret_cast<float*>(Cv)[(size_t)row * ldc + col] = v;
                } else {  // E_PART: raw f32 partial at z offset
                    float* Cp = reinterpret_cast<float*>(Cv) + zo * sCz;
                    Cp[(size_t)row * ldc + col] = v;
                }
            }
        }
    }
}

// ---------------- reduce partials over z, apply ELU, write/accumulate strided slice ----------------
__global__ __launch_bounds__(256) void reduce_elu_kernel(const float* __restrict__ p, float* __restrict__ out,
                                                         int MN, int Z, int logN, int outld, int coloff,
                                                         int accum) {
    int i = blockIdx.x * 256 + threadIdx.x;
    if (i >= MN) return;
    float s = 0.f;
    for (int z = 0; z < Z; ++z) s += p[(size_t)z * MN + i];
    s = s > 0.f ? s : (__expf(s) - 1.f);
    int m = i >> logN, j = i & ((1 << logN) - 1);
    float* o = out + (size_t)m * outld + coloff + j;
    if (accum) *o += s;
    else *o = s;
}

// ---------------- combines ----------------
__global__ __launch_bounds__(256) void combine_obj_kernel(const float* __restrict__ feat,
        const float* __restrict__ a, const float* __restrict__ b,
        const float* __restrict__ c, const float* __restrict__ d,
        float* __restrict__ out, u16* __restrict__ outbf) {
    int i = blockIdx.x * 256 + threadIdx.x;
    int r = i >> 10, col = i & 1023;
    size_t half = (size_t)r * 512 + (col & 511);
    float t1 = (col < 512) ? a[half] : b[half];
    float t2 = (col < 512) ? c[half] : d[half];
    float o = (feat[i] + t1 + t2) * (1.f / 3.f);
    out[i] = o;
    outbf[i] = f2bf(o);
}

__global__ __launch_bounds__(256) void combine_rel1_kernel(const float* __restrict__ feat,
        const float* __restrict__ a, const float* __restrict__ b, u16* __restrict__ outbf) {
    int i = blockIdx.x * 256 + threadIdx.x;
    int r = i >> 10, col = i & 1023;
    size_t half = (size_t)r * 512 + (col & 511);
    float t = (col < 512) ? a[half] : b[half];
    outbf[i] = f2bf((feat[i] + t) * 0.5f);
}

__global__ __launch_bounds__(256) void combine_rel2_kernel(const float* __restrict__ feat,
        const float* __restrict__ a, const float* __restrict__ b, float* __restrict__ out) {
    int i = blockIdx.x * 256 + threadIdx.x;
    int r = i >> 10, col = i & 1023;
    size_t half = (size_t)r * 512 + (col & 511);
    float t = (col < 512) ? a[half] : b[half];
    out[i] = (feat[i] + t) * 0.5f;
}

// ---------------- launch helpers ----------------
static inline void proj(const u16* A, const u16* W, u16* C, const float* bias,
                        int M, int N, int K, bool big, hipStream_t st) {
    if (big)
        gemm_nt<E_PROJ, 128><<<dim3(M / 128, N / 128), 256, 0, st>>>(A, W, C, bias, M, N, K, K, K, N, 0.f, 0, 0, 0);
    else
        gemm_nt<E_PROJ, 64><<<dim3(M / 64, N / 64), 256, 0, st>>>(A, W, C, bias, M, N, K, K, K, N, 0.f, 0, 0, 0);
}

static inline void score(const u16* Q, const u16* Kx, float* S, int M, int N, int dk,
                         int ldq, int ldk, float sc, bool mask, hipStream_t st) {
    if (mask)
        gemm_nt<E_SCM, 128><<<dim3(M / 128, N / 128), 256, 0, st>>>(Q, Kx, S, nullptr, M, N, dk, ldq, ldk, N, sc, 0, 0, 0);
    else
        gemm_nt<E_SC, 128><<<dim3(M / 128, N / 128), 256, 0, st>>>(Q, Kx, S, nullptr, M, N, dk, ldq, ldk, N, sc, 0, 0, 0);
}

// C_part[z][M][N] = A(M, Kc @ z*Kc) * B^T ; then reduce with ELU into out slice
static inline void value_gemm(const u16* P, int ldp, const u16* VT, int ldv, float* part,
                              float* out, int M, int N, int Ktot, int Kc, int logN, int coloff,
                              int accum, hipStream_t st) {
    int Z = Ktot / Kc;
    gemm_nt<E_PART, 64><<<dim3(M / 64, N / 64, Z), 256, 0, st>>>(P, VT, part, nullptr,
        M, N, Kc, ldp, ldv, N, 0.f, (long)Kc, (long)Kc, (long)M * N);
    int MN = M * N;
    reduce_elu_kernel<<<MN / 256, 256, 0, st>>>(part, out, MN, Z, logN, 512, coloff, accum);
}

extern "C" void kernel_launch(void* const* d_in, const int* in_sizes, int n_in,
                              void* d_out, int out_size, void* d_ws, size_t ws_size,
                              hipStream_t stream) {
    (void)in_sizes; (void)n_in; (void)out_size; (void)ws_size;
    const float* feat_obj = (const float*)d_in[0];
    const float* feat_rel = (const float*)d_in[1];
    const float* W_cat = (const float*)d_in[2];
    const float* b_cat = (const float*)d_in[3];
    const float* W_out = (const float*)d_in[4];
    const float* b_out = (const float*)d_in[5];
    float* out_obj = (float*)d_out;
    float* out_rel = (float*)d_out + (size_t)2048 * 1024;

    char* w = (char*)d_ws;
    auto alloc = [&](size_t bytes) { void* p = (void*)w; w += (bytes + 255) & ~(size_t)255; return p; };
    u16* bf_obj  = (u16*)alloc((size_t)2048 * 1024 * 2);
    u16* bf_rel  = (u16*)alloc((size_t)4096 * 1024 * 2);
    u16* bf_obj2 = (u16*)alloc((size_t)2048 * 1024 * 2);
    u16* bf_rel2 = (u16*)alloc((size_t)4096 * 1024 * 2);
    u16* Wt_cat  = (u16*)alloc((size_t)12 * 512 * 1024 * 2);
    u16* Wt_out  = (u16*)alloc((size_t)8 * 3072 * 1024 * 2);
    u16* bufQ    = (u16*)alloc((size_t)4096 * 3072 * 2);
    u16* bufK    = (u16*)alloc((size_t)4096 * 3072 * 2);
    u16* bufV    = (u16*)alloc((size_t)4096 * 3072 * 2);  // stage1: qv ; stage2: qv/kv
    u16* bufV2   = (u16*)alloc((size_t)4096 * 512 * 2);   // stage1: kv
    u16* VTa     = (u16*)alloc((size_t)3072 * 2048 * 2);  // stage1: VkT [512][Nk]; stage2: VT [3072][2048]
    u16* VTb     = (u16*)alloc((size_t)512 * 4096 * 2);   // stage1: VqT [512][Nq]
    float* Sbuf  = (float*)alloc((size_t)2048 * 4096 * 4);
    u16* Pbuf    = (u16*)alloc((size_t)2048 * 4096 * 2);
    u16* PTbuf   = (u16*)alloc((size_t)2048 * 4096 * 2);
    float* part  = (float*)alloc((size_t)2 * 4096 * 512 * 4);  // 16MB: max of z-partials
    float* sub_obj  = (float*)alloc((size_t)2048 * 512 * 4);
    float* obj_sub  = (float*)alloc((size_t)2048 * 512 * 4);
    float* sub_rel  = (float*)alloc((size_t)2048 * 512 * 4);
    float* obj_rel  = (float*)alloc((size_t)2048 * 512 * 4);
    float* rel_obj  = (float*)alloc((size_t)4096 * 512 * 4);
    float* rel_sub  = (float*)alloc((size_t)4096 * 512 * 4);
    float* rel_obj2 = (float*)alloc((size_t)4096 * 512 * 4);
    float* rel_sub2 = (float*)alloc((size_t)4096 * 512 * 4);

    cvt_bf16_kernel<<<2048, 256, 0, stream>>>((const float4*)feat_obj, (ushort4*)bf_obj, 2048 * 1024 / 4);
    cvt_bf16_kernel<<<4096, 256, 0, stream>>>((const float4*)feat_rel, (ushort4*)bf_rel, 4096 * 1024 / 4);
    transcvt_kernel<<<dim3(512 / 32, 1024 / 32, 12), dim3(32, 8), 0, stream>>>(W_cat, Wt_cat, 1024, 512);
    transcvt_kernel<<<dim3(3072 / 32, 1024 / 32, 8), dim3(32, 8), 0, stream>>>(W_out, Wt_out, 1024, 3072);

    const float sc1 = 0.08838834764831845f;  // 1/sqrt(128)
    const float sc2 = 0.04419417382415922f;  // 1/sqrt(512)

    // ---------------- stage 1: three concat=True MHAs, h=4, d_k=128 ----------------
    struct MhaCfg { const u16* xq; const u16* xk; int Nq, Nk; float* d1; float* d2; int mask; };
    MhaCfg cfg[3] = {
        { bf_obj, bf_obj, 2048, 2048, sub_obj, obj_sub, 1 },
        { bf_obj, bf_rel, 2048, 4096, sub_rel, rel_sub, 0 },
        { bf_rel, bf_obj, 4096, 2048, rel_obj, obj_rel, 0 },
    };
    for (int m = 0; m < 3; ++m) {
        const u16* Wt = Wt_cat + (size_t)m * 4 * 512 * 1024;
        const float* bb = b_cat + m * 4 * 512;
        int Nq = cfg[m].Nq, Nk = cfg[m].Nk;
        proj(cfg[m].xq, Wt + (size_t)0 * 512 * 1024, bufQ,  bb + 0,    Nq, 512, 1024, false, stream);
        proj(cfg[m].xk, Wt + (size_t)1 * 512 * 1024, bufK,  bb + 512,  Nk, 512, 1024, false, stream);
        proj(cfg[m].xq, Wt + (size_t)2 * 512 * 1024, bufV,  bb + 1024, Nq, 512, 1024, false, stream);
        proj(cfg[m].xk, Wt + (size_t)3 * 512 * 1024, bufV2, bb + 1536, Nk, 512, 1024, false, stream);
        transpose_bf16_kernel<<<dim3(Nk / 64, 512 / 64), 256, 0, stream>>>(bufV2, VTa, Nk, 512);  // kv^T [512][Nk]
        transpose_bf16_kernel<<<dim3(Nq / 64, 512 / 64), 256, 0, stream>>>(bufV,  VTb, Nq, 512);  // qv^T [512][Nq]
        for (int h = 0; h < 4; ++h) {
            score(bufQ + h * 128, bufK + h * 128, Sbuf, Nq, Nk, 128, 512, 512, sc1, cfg[m].mask, stream);
            softmax_kernel<<<Nq, 256, 0, stream>>>(Sbuf, Pbuf, Nk);
            transpose_bf16_kernel<<<dim3(Nq / 64, Nk / 64), 256, 0, stream>>>(Pbuf, PTbuf, Nq, Nk);
            // a1 = elu(P @ kv_h): M=Nq, N=128, K=Nk
            value_gemm(Pbuf, Nk, VTa + (size_t)h * 128 * Nk, Nk, part,
                       cfg[m].d1, Nq, 128, Nk, 512, 7, h * 128, 0, stream);
            // a2 = elu(P^T @ qv_h): M=Nk, N=128, K=Nq
            value_gemm(PTbuf, Nq, VTb + (size_t)h * 128 * Nq, Nq, part,
                       cfg[m].d2, Nk, 128, Nq, 512, 7, h * 128, 0, stream);
        }
    }

    combine_obj_kernel<<<8192, 256, 0, stream>>>(feat_obj, sub_obj, obj_sub, sub_rel, obj_rel, out_obj, bf_obj2);
    combine_rel1_kernel<<<16384, 256, 0, stream>>>(feat_rel, rel_obj, rel_sub, bf_rel2);

    // ---------------- stage 2: two concat=False MHAs, h=6, d_k=512 ----------------
    // mha0: xq=obj2 (2048), xk=rel2 (4096); need a2 = sum_h elu(P_h^T @ qv_h)
    {
        const u16* Wt = Wt_out;
        const float* bb = b_out;
        proj(bf_obj2, Wt + (size_t)0 * 3072 * 1024, bufQ, bb + 0 * 3072, 2048, 3072, 1024, true, stream);
        proj(bf_rel2, Wt + (size_t)1 * 3072 * 1024, bufK, bb + 1 * 3072, 4096, 3072, 1024, true, stream);
        proj(bf_obj2, Wt + (size_t)2 * 3072 * 1024, bufV, bb + 2 * 3072, 2048, 3072, 1024, true, stream);
        transpose_bf16_kernel<<<dim3(2048 / 64, 3072 / 64), 256, 0, stream>>>(bufV, VTa, 2048, 3072);  // qv^T [3072][2048]
        for (int h = 0; h < 6; ++h) {
            score(bufQ + h * 512, bufK + h * 512, Sbuf, 2048, 4096, 512, 3072, 3072, sc2, false, stream);
            softmax_kernel<<<2048, 256, 0, stream>>>(Sbuf, Pbuf, 4096);
            transpose_bf16_kernel<<<dim3(2048 / 64, 4096 / 64), 256, 0, stream>>>(Pbuf, PTbuf, 2048, 4096);
            // a2_h = elu(P^T @ qv_h): M=4096, N=512, K=2048; accumulate over heads
            value_gemm(PTbuf, 2048, VTa + (size_t)h * 512 * 2048, 2048, part,
                       rel_sub2, 4096, 512, 2048, 1024, 9, 0, h > 0, stream);
        }
    }
    // mha1: xq=rel2 (4096), xk=obj2 (2048); need a1 = sum_h elu(P_h @ kv_h)
    {
        const u16* Wt = Wt_out + (size_t)4 * 3072 * 1024;
        const float* bb = b_out + 4 * 3072;
        proj(bf_rel2, Wt + (size_t)0 * 3072 * 1024, bufQ, bb + 0 * 3072, 4096, 3072, 1024, true, stream);
        proj(bf_obj2, Wt + (size_t)1 * 3072 * 1024, bufK, bb + 1 * 3072, 2048, 3072, 1024, true, stream);
        proj(bf_obj2, Wt + (size_t)3 * 3072 * 1024, bufV, bb + 3 * 3072, 2048, 3072, 1024, true, stream);
        transpose_bf16_kernel<<<dim3(2048 / 64, 3072 / 64), 256, 0, stream>>>(bufV, VTa, 2048, 3072);  // kv^T [3072][2048]
        for (int h = 0; h < 6; ++h) {
            score(bufQ + h * 512, bufK + h * 512, Sbuf, 4096, 2048, 512, 3072, 3072, sc2, false, stream);
            softmax_kernel<<<4096, 256, 0, stream>>>(Sbuf, Pbuf, 2048);
            // a1_h = elu(P @ kv_h): M=4096, N=512, K=2048; accumulate over heads
            value_gemm(Pbuf, 2048, VTa + (size_t)h * 512 * 2048, 2048, part,
                       rel_obj2, 4096, 512, 2048, 1024, 9, 0, h > 0, stream);
        }
    }

    combine_rel2_kernel<<<16384, 256, 0, stream>>>(feat_rel, rel_obj2, rel_sub2, out_rel);
}

// Round 3
// 1819.917 us; speedup vs baseline: 3.7929x; 1.1135x over previous
//
#include <hip/hip_runtime.h>

typedef unsigned short u16;
typedef unsigned int u32;
typedef __attribute__((ext_vector_type(4))) float f32x4;
typedef __attribute__((ext_vector_type(8))) __bf16 bf16x8;
typedef __attribute__((ext_vector_type(8))) unsigned short u16x8;

#if defined(__has_builtin)
#if __has_builtin(__builtin_amdgcn_global_load_lds)
#define HAS_GLL 1
#endif
#endif

__device__ __forceinline__ u16 f2bf(float f) {
    u32 u = __builtin_bit_cast(u32, f);
    u += 0x7fffu + ((u >> 16) & 1u);
    return (u16)(u >> 16);
}
__device__ __forceinline__ float bf2f(u16 x) {
    return __builtin_bit_cast(float, (u32)x << 16);
}

// ---------------- elementwise conversion ----------------
__global__ __launch_bounds__(256) void cvt_bf16_kernel(const float4* __restrict__ in,
                                                       ushort4* __restrict__ out, int n4) {
    int i = blockIdx.x * 256 + threadIdx.x;
    if (i < n4) {
        float4 v = in[i];
        ushort4 o;
        o.x = f2bf(v.x); o.y = f2bf(v.y); o.z = f2bf(v.z); o.w = f2bf(v.w);
        out[i] = o;
    }
}

// transpose + convert: W [B][K][N] f32 -> Wt [B][N][K] bf16
__global__ __launch_bounds__(256) void transcvt_kernel(const float* __restrict__ W,
                                                       u16* __restrict__ Wt, int K, int N) {
    __shared__ u16 t[32][33];
    int b = blockIdx.z;
    const float* Wb = W + (size_t)b * K * N;
    u16* Wtb = Wt + (size_t)b * K * N;
    int n0 = blockIdx.x * 32, k0 = blockIdx.y * 32;
    int tx = threadIdx.x, ty = threadIdx.y;
#pragma unroll
    for (int j = 0; j < 4; ++j)
        t[ty + j * 8][tx] = f2bf(Wb[(size_t)(k0 + ty + j * 8) * N + n0 + tx]);
    __syncthreads();
#pragma unroll
    for (int j = 0; j < 4; ++j)
        Wtb[(size_t)(n0 + ty + j * 8) * K + k0 + tx] = t[tx][ty + j * 8];
}

// bf16 transpose: in [R][C] -> out [C][R]; R,C multiples of 64
__global__ __launch_bounds__(256) void transpose_bf16_kernel(const u16* __restrict__ in,
                                                             u16* __restrict__ out, int R, int C) {
    __shared__ u16 t[64][65];
    int r0 = blockIdx.x * 64, c0 = blockIdx.y * 64;
    int tx = threadIdx.x & 15, ty = threadIdx.x >> 4;
#pragma unroll
    for (int j = 0; j < 4; ++j) {
        int r = ty + j * 16;
        ushort4 v = *reinterpret_cast<const ushort4*>(in + (size_t)(r0 + r) * C + c0 + tx * 4);
        t[r][tx * 4 + 0] = v.x; t[r][tx * 4 + 1] = v.y;
        t[r][tx * 4 + 2] = v.z; t[r][tx * 4 + 3] = v.w;
    }
    __syncthreads();
#pragma unroll
    for (int j = 0; j < 4; ++j) {
        int c = ty + j * 16;
        ushort4 v;
        v.x = t[tx * 4 + 0][c]; v.y = t[tx * 4 + 1][c];
        v.z = t[tx * 4 + 2][c]; v.w = t[tx * 4 + 3][c];
        *reinterpret_cast<ushort4*>(out + (size_t)(c0 + c) * R + r0 + tx * 4) = v;
    }
}

// ---------------- row softmax: S [M][N] bf16 -> P [M][N] bf16, vectorized ----------------
__global__ __launch_bounds__(256) void softmax_kernel(const u16* __restrict__ S,
                                                      u16* __restrict__ P, int N) {
    int row = blockIdx.x;
    const u16* s = S + (size_t)row * N;
    u16* p = P + (size_t)row * N;
    int tid = threadIdx.x, lane = tid & 63, wid = tid >> 6;
    int cnt = N >> 11;                 // chunks of 2048: N=2048 -> 1, 4096 -> 2
    __shared__ float red[4];
    __shared__ float bcast[2];
    float v[16];
    float mx = -3.0e38f;
    for (int c = 0; c < cnt; ++c) {
        u16x8 x = *reinterpret_cast<const u16x8*>(s + c * 2048 + tid * 8);
#pragma unroll
        for (int j = 0; j < 8; ++j) {
            float f = bf2f(x[j]);
            v[c * 8 + j] = f;
            mx = fmaxf(mx, f);
        }
    }
#pragma unroll
    for (int off = 32; off; off >>= 1) mx = fmaxf(mx, __shfl_down(mx, off));
    if (lane == 0) red[wid] = mx;
    __syncthreads();
    if (tid == 0) bcast[0] = fmaxf(fmaxf(red[0], red[1]), fmaxf(red[2], red[3]));
    __syncthreads();
    mx = bcast[0];
    float sum = 0.f;
    for (int i = 0; i < cnt * 8; ++i) {
        float e = __expf(v[i] - mx);
        v[i] = e;
        sum += e;
    }
#pragma unroll
    for (int off = 32; off; off >>= 1) sum += __shfl_down(sum, off);
    if (lane == 0) red[wid] = sum;
    __syncthreads();
    if (tid == 0) bcast[1] = red[0] + red[1] + red[2] + red[3];
    __syncthreads();
    float rinv = 1.f / bcast[1];
    for (int c = 0; c < cnt; ++c) {
        u16x8 o;
#pragma unroll
        for (int j = 0; j < 8; ++j) o[j] = f2bf(v[c * 8 + j] * rinv);
        *reinterpret_cast<u16x8*>(p + c * 2048 + tid * 8) = o;
    }
}

// ---------------- GEMM: C = A (M,K) * B^T (N,K), row-major, 2-phase prefetch ----------------
// LDS: linear [BM][32] u16 per buffer, XOR-swizzled k-chunks (phys = logical ^ ((row>>1)&3)),
// staged via global_load_lds width 16 (pre-swizzled global source), read via swizzled ds_read_b128.
// Double-buffered: tile t+1 loads issued before tile t compute; one barrier per K-step.
enum { E_PROJ = 0, E_SC, E_SCM, E_PART };

template <int EPI, int BM>
__global__ __launch_bounds__(256) void gemm_nt(const u16* __restrict__ A, const u16* __restrict__ B,
                                               void* __restrict__ Cv, const float* __restrict__ bias,
                                               int M, int N, int K, int lda, int ldb, int ldc,
                                               float scale, long sAz, long sBz, long sCz) {
    constexpr int MF = BM / 32;               // 16x16 frags per wave dim: 4 (BM=128) or 2 (BM=64)
    constexpr int ITERS = BM * 32 / (256 * 8);
    __shared__ __align__(16) u16 As[2][BM * 32];
    __shared__ __align__(16) u16 Bs[2][BM * 32];
    const int tid = threadIdx.x;
    const int lane = tid & 63;
    const int wid = tid >> 6;
    const int wr = (wid >> 1) * (BM / 2);
    const int wc = (wid & 1) * (BM / 2);
    const int row0 = blockIdx.x * BM;
    const int col0 = blockIdx.y * BM;
    const long zo = blockIdx.z;
    const u16* Az = A + zo * sAz;
    const u16* Bz = B + zo * sBz;
    f32x4 acc[MF][MF] = {};

    auto stage = [&](int buf, int k0) {
#pragma unroll
        for (int i = 0; i < ITERS; ++i) {
            int c = tid + i * 256;
            int r = c >> 2;
            int lch = (c & 3) ^ ((r >> 1) & 3);   // logical k-chunk held by this physical slot
            const u16* sa = Az + (size_t)(row0 + r) * lda + k0 + lch * 8;
            const u16* sb = Bz + (size_t)(col0 + r) * ldb + k0 + lch * 8;
#ifdef HAS_GLL
            __builtin_amdgcn_global_load_lds(
                (const __attribute__((address_space(1))) void*)sa,
                (__attribute__((address_space(3))) void*)(&As[buf][c * 8]), 16, 0, 0);
            __builtin_amdgcn_global_load_lds(
                (const __attribute__((address_space(1))) void*)sb,
                (__attribute__((address_space(3))) void*)(&Bs[buf][c * 8]), 16, 0, 0);
#else
            *reinterpret_cast<uint4*>(&As[buf][c * 8]) = *reinterpret_cast<const uint4*>(sa);
            *reinterpret_cast<uint4*>(&Bs[buf][c * 8]) = *reinterpret_cast<const uint4*>(sb);
#endif
        }
    };

    stage(0, 0);
    __syncthreads();
    int cur = 0;
    for (int k0 = 0; k0 < K; k0 += 32) {
        if (k0 + 32 < K) stage(cur ^ 1, k0 + 32);
        bf16x8 af[MF], bv[MF];
#pragma unroll
        for (int m = 0; m < MF; ++m) {
            int rr = wr + m * 16 + (lane & 15);
            int p = (lane >> 4) ^ ((rr >> 1) & 3);
            af[m] = *reinterpret_cast<const bf16x8*>(&As[cur][rr * 32 + p * 8]);
        }
#pragma unroll
        for (int n = 0; n < MF; ++n) {
            int rr = wc + n * 16 + (lane & 15);
            int p = (lane >> 4) ^ ((rr >> 1) & 3);
            bv[n] = *reinterpret_cast<const bf16x8*>(&Bs[cur][rr * 32 + p * 8]);
        }
#pragma unroll
        for (int m = 0; m < MF; ++m)
#pragma unroll
            for (int n = 0; n < MF; ++n)
                acc[m][n] = __builtin_amdgcn_mfma_f32_16x16x32_bf16(af[m], bv[n], acc[m][n], 0, 0, 0);
        __syncthreads();          // drains prefetch (vmcnt) + protects buffer swap
        cur ^= 1;
    }

#pragma unroll
    for (int m = 0; m < MF; ++m) {
#pragma unroll
        for (int n = 0; n < MF; ++n) {
#pragma unroll
            for (int j = 0; j < 4; ++j) {
                int row = row0 + wr + m * 16 + ((lane >> 4) << 2) + j;
                int col = col0 + wc + n * 16 + (lane & 15);
                float v = acc[m][n][j];
                if (EPI == E_PROJ) {
                    v += bias[col];
                    reinterpret_cast<u16*>(Cv)[(size_t)row * ldc + col] = f2bf(v);
                } else if (EPI == E_SC || EPI == E_SCM) {
                    v *= scale;
                    if (EPI == E_SCM && row == col) v = -1e9f;
                    reinterpret_cast<u16*>(Cv)[(size_t)row * ldc + col] = f2bf(v);
                } else {  // E_PART: raw f32 partial at z offset
                    float* Cp = reinterpret_cast<float*>(Cv) + zo * sCz;
                    Cp[(size_t)row * ldc + col] = v;
                }
            }
        }
    }
}

// ---------------- reduce partials over z, apply ELU, write/accumulate strided slice ----------------
__global__ __launch_bounds__(256) void reduce_elu_kernel(const float* __restrict__ p, float* __restrict__ out,
                                                         int MN, int Z, int logN, int outld, int coloff,
                                                         int accum) {
    int i = blockIdx.x * 256 + threadIdx.x;
    if (i >= MN) return;
    float s = 0.f;
    for (int z = 0; z < Z; ++z) s += p[(size_t)z * MN + i];
    s = s > 0.f ? s : (__expf(s) - 1.f);
    int m = i >> logN, j = i & ((1 << logN) - 1);
    float* o = out + (size_t)m * outld + coloff + j;
    if (accum) *o += s;
    else *o = s;
}

// ---------------- combines ----------------
__global__ __launch_bounds__(256) void combine_obj_kernel(const float* __restrict__ feat,
        const float* __restrict__ a, const float* __restrict__ b,
        const float* __restrict__ c, const float* __restrict__ d,
        float* __restrict__ out, u16* __restrict__ outbf) {
    int i = blockIdx.x * 256 + threadIdx.x;
    int r = i >> 10, col = i & 1023;
    size_t half = (size_t)r * 512 + (col & 511);
    float t1 = (col < 512) ? a[half] : b[half];
    float t2 = (col < 512) ? c[half] : d[half];
    float o = (feat[i] + t1 + t2) * (1.f / 3.f);
    out[i] = o;
    outbf[i] = f2bf(o);
}

__global__ __launch_bounds__(256) void combine_rel1_kernel(const float* __restrict__ feat,
        const float* __restrict__ a, const float* __restrict__ b, u16* __restrict__ outbf) {
    int i = blockIdx.x * 256 + threadIdx.x;
    int r = i >> 10, col = i & 1023;
    size_t half = (size_t)r * 512 + (col & 511);
    float t = (col < 512) ? a[half] : b[half];
    outbf[i] = f2bf((feat[i] + t) * 0.5f);
}

__global__ __launch_bounds__(256) void combine_rel2_kernel(const float* __restrict__ feat,
        const float* __restrict__ a, const float* __restrict__ b, float* __restrict__ out) {
    int i = blockIdx.x * 256 + threadIdx.x;
    int r = i >> 10, col = i & 1023;
    size_t half = (size_t)r * 512 + (col & 511);
    float t = (col < 512) ? a[half] : b[half];
    out[i] = (feat[i] + t) * 0.5f;
}

// ---------------- launch helpers ----------------
static inline void proj(const u16* A, const u16* W, u16* C, const float* bias,
                        int M, int N, int K, bool big, hipStream_t st) {
    if (big)
        gemm_nt<E_PROJ, 128><<<dim3(M / 128, N / 128), 256, 0, st>>>(A, W, C, bias, M, N, K, K, K, N, 0.f, 0, 0, 0);
    else
        gemm_nt<E_PROJ, 64><<<dim3(M / 64, N / 64), 256, 0, st>>>(A, W, C, bias, M, N, K, K, K, N, 0.f, 0, 0, 0);
}

static inline void score(const u16* Q, const u16* Kx, u16* S, int M, int N, int dk,
                         int ldq, int ldk, float sc, bool mask, hipStream_t st) {
    if (mask)
        gemm_nt<E_SCM, 128><<<dim3(M / 128, N / 128), 256, 0, st>>>(Q, Kx, S, nullptr, M, N, dk, ldq, ldk, N, sc, 0, 0, 0);
    else
        gemm_nt<E_SC, 128><<<dim3(M / 128, N / 128), 256, 0, st>>>(Q, Kx, S, nullptr, M, N, dk, ldq, ldk, N, sc, 0, 0, 0);
}

// C_part[z][M][N] = A(M, Kc @ z*Kc) * B^T ; then reduce with ELU into out slice
static inline void value_gemm(const u16* P, int ldp, const u16* VT, int ldv, float* part,
                              float* out, int M, int N, int Ktot, int Kc, int logN, int coloff,
                              int accum, bool big, hipStream_t st) {
    int Z = Ktot / Kc;
    if (big)
        gemm_nt<E_PART, 128><<<dim3(M / 128, N / 128, Z), 256, 0, st>>>(P, VT, part, nullptr,
            M, N, Kc, ldp, ldv, N, 0.f, (long)Kc, (long)Kc, (long)M * N);
    else
        gemm_nt<E_PART, 64><<<dim3(M / 64, N / 64, Z), 256, 0, st>>>(P, VT, part, nullptr,
            M, N, Kc, ldp, ldv, N, 0.f, (long)Kc, (long)Kc, (long)M * N);
    int MN = M * N;
    reduce_elu_kernel<<<MN / 256, 256, 0, st>>>(part, out, MN, Z, logN, 512, coloff, accum);
}

extern "C" void kernel_launch(void* const* d_in, const int* in_sizes, int n_in,
                              void* d_out, int out_size, void* d_ws, size_t ws_size,
                              hipStream_t stream) {
    (void)in_sizes; (void)n_in; (void)out_size; (void)ws_size;
    const float* feat_obj = (const float*)d_in[0];
    const float* feat_rel = (const float*)d_in[1];
    const float* W_cat = (const float*)d_in[2];
    const float* b_cat = (const float*)d_in[3];
    const float* W_out = (const float*)d_in[4];
    const float* b_out = (const float*)d_in[5];
    float* out_obj = (float*)d_out;
    float* out_rel = (float*)d_out + (size_t)2048 * 1024;

    char* w = (char*)d_ws;
    auto alloc = [&](size_t bytes) { void* p = (void*)w; w += (bytes + 255) & ~(size_t)255; return p; };
    u16* bf_obj  = (u16*)alloc((size_t)2048 * 1024 * 2);
    u16* bf_rel  = (u16*)alloc((size_t)4096 * 1024 * 2);
    u16* bf_obj2 = (u16*)alloc((size_t)2048 * 1024 * 2);
    u16* bf_rel2 = (u16*)alloc((size_t)4096 * 1024 * 2);
    u16* Wt_cat  = (u16*)alloc((size_t)12 * 512 * 1024 * 2);
    u16* Wt_out  = (u16*)alloc((size_t)8 * 3072 * 1024 * 2);
    u16* bufQ    = (u16*)alloc((size_t)4096 * 3072 * 2);
    u16* bufK    = (u16*)alloc((size_t)4096 * 3072 * 2);
    u16* bufV    = (u16*)alloc((size_t)4096 * 3072 * 2);  // stage1: qv ; stage2: qv/kv
    u16* bufV2   = (u16*)alloc((size_t)4096 * 512 * 2);   // stage1: kv
    u16* VTa     = (u16*)alloc((size_t)3072 * 2048 * 2);  // stage1: VkT [512][Nk]; stage2: VT [3072][2048]
    u16* VTb     = (u16*)alloc((size_t)512 * 4096 * 2);   // stage1: VqT [512][Nq]
    u16* Sbuf    = (u16*)alloc((size_t)2048 * 4096 * 2);
    u16* Pbuf    = (u16*)alloc((size_t)2048 * 4096 * 2);
    u16* PTbuf   = (u16*)alloc((size_t)2048 * 4096 * 2);
    float* part  = (float*)alloc((size_t)2 * 4096 * 512 * 4);  // 16MB z-partials
    float* sub_obj  = (float*)alloc((size_t)2048 * 512 * 4);
    float* obj_sub  = (float*)alloc((size_t)2048 * 512 * 4);
    float* sub_rel  = (float*)alloc((size_t)2048 * 512 * 4);
    float* obj_rel  = (float*)alloc((size_t)2048 * 512 * 4);
    float* rel_obj  = (float*)alloc((size_t)4096 * 512 * 4);
    float* rel_sub  = (float*)alloc((size_t)4096 * 512 * 4);
    float* rel_obj2 = (float*)alloc((size_t)4096 * 512 * 4);
    float* rel_sub2 = (float*)alloc((size_t)4096 * 512 * 4);

    cvt_bf16_kernel<<<2048, 256, 0, stream>>>((const float4*)feat_obj, (ushort4*)bf_obj, 2048 * 1024 / 4);
    cvt_bf16_kernel<<<4096, 256, 0, stream>>>((const float4*)feat_rel, (ushort4*)bf_rel, 4096 * 1024 / 4);
    transcvt_kernel<<<dim3(512 / 32, 1024 / 32, 12), dim3(32, 8), 0, stream>>>(W_cat, Wt_cat, 1024, 512);
    transcvt_kernel<<<dim3(3072 / 32, 1024 / 32, 8), dim3(32, 8), 0, stream>>>(W_out, Wt_out, 1024, 3072);

    const float sc1 = 0.08838834764831845f;  // 1/sqrt(128)
    const float sc2 = 0.04419417382415922f;  // 1/sqrt(512)

    // ---------------- stage 1: three concat=True MHAs, h=4, d_k=128 ----------------
    struct MhaCfg { const u16* xq; const u16* xk; int Nq, Nk; float* d1; float* d2; int mask; };
    MhaCfg cfg[3] = {
        { bf_obj, bf_obj, 2048, 2048, sub_obj, obj_sub, 1 },
        { bf_obj, bf_rel, 2048, 4096, sub_rel, rel_sub, 0 },
        { bf_rel, bf_obj, 4096, 2048, rel_obj, obj_rel, 0 },
    };
    for (int m = 0; m < 3; ++m) {
        const u16* Wt = Wt_cat + (size_t)m * 4 * 512 * 1024;
        const float* bb = b_cat + m * 4 * 512;
        int Nq = cfg[m].Nq, Nk = cfg[m].Nk;
        proj(cfg[m].xq, Wt + (size_t)0 * 512 * 1024, bufQ,  bb + 0,    Nq, 512, 1024, false, stream);
        proj(cfg[m].xk, Wt + (size_t)1 * 512 * 1024, bufK,  bb + 512,  Nk, 512, 1024, false, stream);
        proj(cfg[m].xq, Wt + (size_t)2 * 512 * 1024, bufV,  bb + 1024, Nq, 512, 1024, false, stream);
        proj(cfg[m].xk, Wt + (size_t)3 * 512 * 1024, bufV2, bb + 1536, Nk, 512, 1024, false, stream);
        transpose_bf16_kernel<<<dim3(Nk / 64, 512 / 64), 256, 0, stream>>>(bufV2, VTa, Nk, 512);  // kv^T [512][Nk]
        transpose_bf16_kernel<<<dim3(Nq / 64, 512 / 64), 256, 0, stream>>>(bufV,  VTb, Nq, 512);  // qv^T [512][Nq]
        for (int h = 0; h < 4; ++h) {
            score(bufQ + h * 128, bufK + h * 128, Sbuf, Nq, Nk, 128, 512, 512, sc1, cfg[m].mask != 0, stream);
            softmax_kernel<<<Nq, 256, 0, stream>>>(Sbuf, Pbuf, Nk);
            transpose_bf16_kernel<<<dim3(Nq / 64, Nk / 64), 256, 0, stream>>>(Pbuf, PTbuf, Nq, Nk);
            // a1 = elu(P @ kv_h): M=Nq, N=128, K=Nk
            value_gemm(Pbuf, Nk, VTa + (size_t)h * 128 * Nk, Nk, part,
                       cfg[m].d1, Nq, 128, Nk, 512, 7, h * 128, 0, false, stream);
            // a2 = elu(P^T @ qv_h): M=Nk, N=128, K=Nq
            value_gemm(PTbuf, Nq, VTb + (size_t)h * 128 * Nq, Nq, part,
                       cfg[m].d2, Nk, 128, Nq, 512, 7, h * 128, 0, false, stream);
        }
    }

    combine_obj_kernel<<<8192, 256, 0, stream>>>(feat_obj, sub_obj, obj_sub, sub_rel, obj_rel, out_obj, bf_obj2);
    combine_rel1_kernel<<<16384, 256, 0, stream>>>(feat_rel, rel_obj, rel_sub, bf_rel2);

    // ---------------- stage 2: two concat=False MHAs, h=6, d_k=512 ----------------
    // mha0: xq=obj2 (2048), xk=rel2 (4096); need a2 = sum_h elu(P_h^T @ qv_h)
    {
        const u16* Wt = Wt_out;
        const float* bb = b_out;
        proj(bf_obj2, Wt + (size_t)0 * 3072 * 1024, bufQ, bb + 0 * 3072, 2048, 3072, 1024, true, stream);
        proj(bf_rel2, Wt + (size_t)1 * 3072 * 1024, bufK, bb + 1 * 3072, 4096, 3072, 1024, true, stream);
        proj(bf_obj2, Wt + (size_t)2 * 3072 * 1024, bufV, bb + 2 * 3072, 2048, 3072, 1024, true, stream);
        transpose_bf16_kernel<<<dim3(2048 / 64, 3072 / 64), 256, 0, stream>>>(bufV, VTa, 2048, 3072);  // qv^T [3072][2048]
        for (int h = 0; h < 6; ++h) {
            score(bufQ + h * 512, bufK + h * 512, Sbuf, 2048, 4096, 512, 3072, 3072, sc2, false, stream);
            softmax_kernel<<<2048, 256, 0, stream>>>(Sbuf, Pbuf, 4096);
            transpose_bf16_kernel<<<dim3(2048 / 64, 4096 / 64), 256, 0, stream>>>(Pbuf, PTbuf, 2048, 4096);
            // a2_h = elu(P^T @ qv_h): M=4096, N=512, K=2048; accumulate over heads
            value_gemm(PTbuf, 2048, VTa + (size_t)h * 512 * 2048, 2048, part,
                       rel_sub2, 4096, 512, 2048, 1024, 9, 0, h > 0, true, stream);
        }
    }
    // mha1: xq=rel2 (4096), xk=obj2 (2048); need a1 = sum_h elu(P_h @ kv_h)
    {
        const u16* Wt = Wt_out + (size_t)4 * 3072 * 1024;
        const float* bb = b_out + 4 * 3072;
        proj(bf_rel2, Wt + (size_t)0 * 3072 * 1024, bufQ, bb + 0 * 3072, 4096, 3072, 1024, true, stream);
        proj(bf_obj2, Wt + (size_t)1 * 3072 * 1024, bufK, bb + 1 * 3072, 2048, 3072, 1024, true, stream);
        proj(bf_obj2, Wt + (size_t)3 * 3072 * 1024, bufV, bb + 3 * 3072, 2048, 3072, 1024, true, stream);
        transpose_bf16_kernel<<<dim3(2048 / 64, 3072 / 64), 256, 0, stream>>>(bufV, VTa, 2048, 3072);  // kv^T [3072][2048]
        for (int h = 0; h < 6; ++h) {
            score(bufQ + h * 512, bufK + h * 512, Sbuf, 4096, 2048, 512, 3072, 3072, sc2, false, stream);
            softmax_kernel<<<4096, 256, 0, stream>>>(Sbuf, Pbuf, 2048);
            // a1_h = elu(P @ kv_h): M=4096, N=512, K=2048; accumulate over heads
            value_gemm(Pbuf, 2048, VTa + (size_t)h * 512 * 2048, 2048, part,
                       rel_obj2, 4096, 512, 2048, 1024, 9, 0, h > 0, true, stream);
        }
    }

    combine_rel2_kernel<<<16384, 256, 0, stream>>>(feat_rel, rel_obj2, rel_sub2, out_rel);
}

// Round 4
// 1179.920 us; speedup vs baseline: 5.8502x; 1.5424x over previous
//
#include <hip/hip_runtime.h>

typedef unsigned short u16;
typedef unsigned int u32;
typedef __attribute__((ext_vector_type(4))) float f32x4;
typedef __attribute__((ext_vector_type(8))) __bf16 bf16x8;
typedef __attribute__((ext_vector_type(8))) unsigned short u16x8;

#if defined(__has_builtin)
#if __has_builtin(__builtin_amdgcn_global_load_lds)
#define HAS_GLL 1
#endif
#endif

__device__ __forceinline__ u16 f2bf(float f) {
    u32 u = __builtin_bit_cast(u32, f);
    u += 0x7fffu + ((u >> 16) & 1u);
    return (u16)(u >> 16);
}
__device__ __forceinline__ float bf2f(u16 x) {
    return __builtin_bit_cast(float, (u32)x << 16);
}

// ---------------- elementwise conversion ----------------
__global__ __launch_bounds__(256) void cvt_bf16_kernel(const float4* __restrict__ in,
                                                       ushort4* __restrict__ out, int n4) {
    int i = blockIdx.x * 256 + threadIdx.x;
    if (i < n4) {
        float4 v = in[i];
        ushort4 o;
        o.x = f2bf(v.x); o.y = f2bf(v.y); o.z = f2bf(v.z); o.w = f2bf(v.w);
        out[i] = o;
    }
}

// transpose + convert: W [B][K][N] f32 -> Wt [B][N][K] bf16
__global__ __launch_bounds__(256) void transcvt_kernel(const float* __restrict__ W,
                                                       u16* __restrict__ Wt, int K, int N) {
    __shared__ u16 t[32][33];
    int b = blockIdx.z;
    const float* Wb = W + (size_t)b * K * N;
    u16* Wtb = Wt + (size_t)b * K * N;
    int n0 = blockIdx.x * 32, k0 = blockIdx.y * 32;
    int tx = threadIdx.x, ty = threadIdx.y;
#pragma unroll
    for (int j = 0; j < 4; ++j)
        t[ty + j * 8][tx] = f2bf(Wb[(size_t)(k0 + ty + j * 8) * N + n0 + tx]);
    __syncthreads();
#pragma unroll
    for (int j = 0; j < 4; ++j)
        Wtb[(size_t)(n0 + ty + j * 8) * K + k0 + tx] = t[tx][ty + j * 8];
}

// bf16 transpose per z-plane: in [z][R][C] -> out [z][C][R]
__global__ __launch_bounds__(256) void transpose_bf16_kernel(const u16* __restrict__ in,
                                                             u16* __restrict__ out, int R, int C,
                                                             long plane) {
    __shared__ u16 t[64][65];
    const u16* inz = in + (size_t)blockIdx.z * plane;
    u16* outz = out + (size_t)blockIdx.z * plane;
    int r0 = blockIdx.x * 64, c0 = blockIdx.y * 64;
    int tx = threadIdx.x & 15, ty = threadIdx.x >> 4;
#pragma unroll
    for (int j = 0; j < 4; ++j) {
        int r = ty + j * 16;
        ushort4 v = *reinterpret_cast<const ushort4*>(inz + (size_t)(r0 + r) * C + c0 + tx * 4);
        t[r][tx * 4 + 0] = v.x; t[r][tx * 4 + 1] = v.y;
        t[r][tx * 4 + 2] = v.z; t[r][tx * 4 + 3] = v.w;
    }
    __syncthreads();
#pragma unroll
    for (int j = 0; j < 4; ++j) {
        int c = ty + j * 16;
        ushort4 v;
        v.x = t[tx * 4 + 0][c]; v.y = t[tx * 4 + 1][c];
        v.z = t[tx * 4 + 2][c]; v.w = t[tx * 4 + 3][c];
        *reinterpret_cast<ushort4*>(outz + (size_t)(c0 + c) * R + r0 + tx * 4) = v;
    }
}

// ---------------- in-place row softmax over z-planes: S[z][M][N] bf16 ----------------
__global__ __launch_bounds__(256) void softmax_kernel(u16* __restrict__ S, int N, long plane) {
    u16* s = S + (size_t)blockIdx.y * plane + (size_t)blockIdx.x * N;
    int tid = threadIdx.x, lane = tid & 63, wid = tid >> 6;
    int cnt = N >> 11;                 // N in {2048,4096} -> 1 or 2 chunks of 8
    __shared__ float red[4];
    __shared__ float bcast[2];
    float v[16];
    float mx = -3.0e38f;
    for (int c = 0; c < cnt; ++c) {
        u16x8 x = *reinterpret_cast<const u16x8*>(s + c * 2048 + tid * 8);
#pragma unroll
        for (int j = 0; j < 8; ++j) {
            float f = bf2f(x[j]);
            v[c * 8 + j] = f;
            mx = fmaxf(mx, f);
        }
    }
#pragma unroll
    for (int off = 32; off; off >>= 1) mx = fmaxf(mx, __shfl_down(mx, off));
    if (lane == 0) red[wid] = mx;
    __syncthreads();
    if (tid == 0) bcast[0] = fmaxf(fmaxf(red[0], red[1]), fmaxf(red[2], red[3]));
    __syncthreads();
    mx = bcast[0];
    float sum = 0.f;
    for (int i = 0; i < cnt * 8; ++i) {
        float e = __expf(v[i] - mx);
        v[i] = e;
        sum += e;
    }
#pragma unroll
    for (int off = 32; off; off >>= 1) sum += __shfl_down(sum, off);
    if (lane == 0) red[wid] = sum;
    __syncthreads();
    if (tid == 0) bcast[1] = red[0] + red[1] + red[2] + red[3];
    __syncthreads();
    float rinv = 1.f / bcast[1];
    for (int c = 0; c < cnt; ++c) {
        u16x8 o;
#pragma unroll
        for (int j = 0; j < 8; ++j) o[j] = f2bf(v[c * 8 + j] * rinv);
        *reinterpret_cast<u16x8*>(s + c * 2048 + tid * 8) = o;
    }
}

// ---------------- GEMM: C = A (M,K) * B^T (N,K), row-major, 2-phase prefetch ----------------
// z-batched: A += z*sAz, B += z*sBz, C elem offset += z*sCz, bias += z*sBias.
enum { E_PROJ = 0, E_SC, E_SCM, E_ELW, E_PART };

template <int EPI, int BM>
__global__ __launch_bounds__(256) void gemm_nt(const u16* __restrict__ A, const u16* __restrict__ B,
                                               void* __restrict__ Cv, const float* __restrict__ bias,
                                               int M, int N, int K, int lda, int ldb, int ldc,
                                               float scale, long sAz, long sBz, long sCz, long sBias) {
    constexpr int MF = BM / 32;               // 16x16 frags per wave dim
    constexpr int ITERS = BM * 32 / (256 * 8);
    __shared__ __align__(16) u16 As[2][BM * 32];
    __shared__ __align__(16) u16 Bs[2][BM * 32];
    const int tid = threadIdx.x;
    const int lane = tid & 63;
    const int wid = tid >> 6;
    const int wr = (wid >> 1) * (BM / 2);
    const int wc = (wid & 1) * (BM / 2);
    const int row0 = blockIdx.x * BM;
    const int col0 = blockIdx.y * BM;
    const long zo = blockIdx.z;
    const u16* Az = A + zo * sAz;
    const u16* Bz = B + zo * sBz;
    const long zoff = zo * sCz;
    const float* biasz = bias ? bias + zo * sBias : nullptr;
    f32x4 acc[MF][MF] = {};

    auto stage = [&](int buf, int k0) {
#pragma unroll
        for (int i = 0; i < ITERS; ++i) {
            int c = tid + i * 256;
            int r = c >> 2;
            int lch = (c & 3) ^ ((r >> 1) & 3);   // logical k-chunk at this physical slot
            const u16* sa = Az + (size_t)(row0 + r) * lda + k0 + lch * 8;
            const u16* sb = Bz + (size_t)(col0 + r) * ldb + k0 + lch * 8;
#ifdef HAS_GLL
            __builtin_amdgcn_global_load_lds(
                (const __attribute__((address_space(1))) void*)sa,
                (__attribute__((address_space(3))) void*)(&As[buf][c * 8]), 16, 0, 0);
            __builtin_amdgcn_global_load_lds(
                (const __attribute__((address_space(1))) void*)sb,
                (__attribute__((address_space(3))) void*)(&Bs[buf][c * 8]), 16, 0, 0);
#else
            *reinterpret_cast<uint4*>(&As[buf][c * 8]) = *reinterpret_cast<const uint4*>(sa);
            *reinterpret_cast<uint4*>(&Bs[buf][c * 8]) = *reinterpret_cast<const uint4*>(sb);
#endif
        }
    };

    stage(0, 0);
    __syncthreads();
    int cur = 0;
    for (int k0 = 0; k0 < K; k0 += 32) {
        if (k0 + 32 < K) stage(cur ^ 1, k0 + 32);
        bf16x8 af[MF], bv[MF];
#pragma unroll
        for (int m = 0; m < MF; ++m) {
            int rr = wr + m * 16 + (lane & 15);
            int p = (lane >> 4) ^ ((rr >> 1) & 3);
            af[m] = *reinterpret_cast<const bf16x8*>(&As[cur][rr * 32 + p * 8]);
        }
#pragma unroll
        for (int n = 0; n < MF; ++n) {
            int rr = wc + n * 16 + (lane & 15);
            int p = (lane >> 4) ^ ((rr >> 1) & 3);
            bv[n] = *reinterpret_cast<const bf16x8*>(&Bs[cur][rr * 32 + p * 8]);
        }
#pragma unroll
        for (int m = 0; m < MF; ++m)
#pragma unroll
            for (int n = 0; n < MF; ++n)
                acc[m][n] = __builtin_amdgcn_mfma_f32_16x16x32_bf16(af[m], bv[n], acc[m][n], 0, 0, 0);
        __syncthreads();          // drains prefetch + protects buffer swap
        cur ^= 1;
    }

#pragma unroll
    for (int m = 0; m < MF; ++m) {
#pragma unroll
        for (int n = 0; n < MF; ++n) {
#pragma unroll
            for (int j = 0; j < 4; ++j) {
                int row = row0 + wr + m * 16 + ((lane >> 4) << 2) + j;
                int col = col0 + wc + n * 16 + (lane & 15);
                float v = acc[m][n][j];
                if (EPI == E_PROJ) {
                    v += biasz[col];
                    reinterpret_cast<u16*>(Cv)[zoff + (size_t)row * ldc + col] = f2bf(v);
                } else if (EPI == E_SC || EPI == E_SCM) {
                    v *= scale;
                    if (EPI == E_SCM && row == col) v = -1e9f;
                    reinterpret_cast<u16*>(Cv)[zoff + (size_t)row * ldc + col] = f2bf(v);
                } else if (EPI == E_ELW) {
                    v = v > 0.f ? v : (__expf(v) - 1.f);
                    reinterpret_cast<float*>(Cv)[zoff + (size_t)row * ldc + col] = v;
                } else {  // E_PART: raw f32 partial per z-plane
                    reinterpret_cast<float*>(Cv)[zoff + (size_t)row * ldc + col] = v;
                }
            }
        }
    }
}

// ---------------- reduce: out (+)= sum_z elu(part[z]); contiguous f32, float4 ----------------
__global__ __launch_bounds__(256) void reduce_elu4_kernel(const float4* __restrict__ part,
                                                          float4* __restrict__ out, int MN4, int Z,
                                                          long plane4, int accum) {
    int i = blockIdx.x * 256 + threadIdx.x;
    if (i >= MN4) return;
    float4 s = accum ? out[i] : float4{0.f, 0.f, 0.f, 0.f};
    for (int z = 0; z < Z; ++z) {
        float4 p = part[(size_t)z * plane4 + i];
        s.x += p.x > 0.f ? p.x : (__expf(p.x) - 1.f);
        s.y += p.y > 0.f ? p.y : (__expf(p.y) - 1.f);
        s.z += p.z > 0.f ? p.z : (__expf(p.z) - 1.f);
        s.w += p.w > 0.f ? p.w : (__expf(p.w) - 1.f);
    }
    out[i] = s;
}

// ---------------- combines (float4) ----------------
__global__ __launch_bounds__(256) void combine_obj_kernel(const float4* __restrict__ feat,
        const float4* __restrict__ a, const float4* __restrict__ b,
        const float4* __restrict__ c, const float4* __restrict__ d,
        float4* __restrict__ out, ushort4* __restrict__ outbf) {
    int i = blockIdx.x * 256 + threadIdx.x;      // over 2048*256 float4
    int r = i >> 8, c4 = i & 255;
    size_t half = (size_t)r * 128 + (c4 & 127);
    float4 t1 = (c4 < 128) ? a[half] : b[half];
    float4 t2 = (c4 < 128) ? c[half] : d[half];
    float4 f = feat[i];
    float4 o;
    o.x = (f.x + t1.x + t2.x) * (1.f / 3.f);
    o.y = (f.y + t1.y + t2.y) * (1.f / 3.f);
    o.z = (f.z + t1.z + t2.z) * (1.f / 3.f);
    o.w = (f.w + t1.w + t2.w) * (1.f / 3.f);
    out[i] = o;
    ushort4 ob; ob.x = f2bf(o.x); ob.y = f2bf(o.y); ob.z = f2bf(o.z); ob.w = f2bf(o.w);
    outbf[i] = ob;
}

__global__ __launch_bounds__(256) void combine_rel1_kernel(const float4* __restrict__ feat,
        const float4* __restrict__ a, const float4* __restrict__ b, ushort4* __restrict__ outbf) {
    int i = blockIdx.x * 256 + threadIdx.x;      // over 4096*256 float4
    int r = i >> 8, c4 = i & 255;
    size_t half = (size_t)r * 128 + (c4 & 127);
    float4 t = (c4 < 128) ? a[half] : b[half];
    float4 f = feat[i];
    ushort4 ob;
    ob.x = f2bf((f.x + t.x) * 0.5f); ob.y = f2bf((f.y + t.y) * 0.5f);
    ob.z = f2bf((f.z + t.z) * 0.5f); ob.w = f2bf((f.w + t.w) * 0.5f);
    outbf[i] = ob;
}

__global__ __launch_bounds__(256) void combine_rel2_kernel(const float4* __restrict__ feat,
        const float4* __restrict__ a, const float4* __restrict__ b, float4* __restrict__ out) {
    int i = blockIdx.x * 256 + threadIdx.x;
    int r = i >> 8, c4 = i & 255;
    size_t half = (size_t)r * 128 + (c4 & 127);
    float4 t = (c4 < 128) ? a[half] : b[half];
    float4 f = feat[i];
    float4 o;
    o.x = (f.x + t.x) * 0.5f; o.y = (f.y + t.y) * 0.5f;
    o.z = (f.z + t.z) * 0.5f; o.w = (f.w + t.w) * 0.5f;
    out[i] = o;
}

extern "C" void kernel_launch(void* const* d_in, const int* in_sizes, int n_in,
                              void* d_out, int out_size, void* d_ws, size_t ws_size,
                              hipStream_t stream) {
    (void)in_sizes; (void)n_in; (void)out_size; (void)ws_size;
    const float* feat_obj = (const float*)d_in[0];
    const float* feat_rel = (const float*)d_in[1];
    const float* W_cat = (const float*)d_in[2];
    const float* b_cat = (const float*)d_in[3];
    const float* W_out = (const float*)d_in[4];
    const float* b_out = (const float*)d_in[5];
    float* out_obj = (float*)d_out;
    float* out_rel = (float*)d_out + (size_t)2048 * 1024;

    char* w = (char*)d_ws;
    auto alloc = [&](size_t bytes) { void* p = (void*)w; w += (bytes + 255) & ~(size_t)255; return p; };
    u16* bf_obj  = (u16*)alloc((size_t)2048 * 1024 * 2);
    u16* bf_rel  = (u16*)alloc((size_t)4096 * 1024 * 2);
    u16* bf_obj2 = (u16*)alloc((size_t)2048 * 1024 * 2);
    u16* bf_rel2 = (u16*)alloc((size_t)4096 * 1024 * 2);
    u16* Wt_cat  = (u16*)alloc((size_t)12 * 512 * 1024 * 2);   // 12 MiB
    u16* Wt2     = (u16*)alloc((size_t)4 * 3072 * 1024 * 2);   // 24 MiB, per-MHA stage2 weights
    u16* bufQV   = (u16*)alloc((size_t)2 * 2048 * 3072 * 2);   // 24 MiB
    u16* bufKV   = (u16*)alloc((size_t)2 * 2048 * 3072 * 2);   // 24 MiB
    u16* VTa     = (u16*)alloc((size_t)3072 * 2048 * 2);       // 12 MiB
    u16* VTb     = (u16*)alloc((size_t)512 * 4096 * 2);        // 4 MiB
    u16* Sbuf    = (u16*)alloc((size_t)4 * 2048 * 4096 * 2);   // 64 MiB (S -> P in place)
    u16* PTbuf   = (u16*)alloc((size_t)4 * 2048 * 4096 * 2);   // 64 MiB
    float* part  = (float*)alloc((size_t)3 * 4096 * 512 * 4);  // 24 MiB
    float* sub_obj  = (float*)alloc((size_t)2048 * 512 * 4);
    float* obj_sub  = (float*)alloc((size_t)2048 * 512 * 4);
    float* sub_rel  = (float*)alloc((size_t)2048 * 512 * 4);
    float* obj_rel  = (float*)alloc((size_t)2048 * 512 * 4);
    float* rel_obj  = (float*)alloc((size_t)4096 * 512 * 4);
    float* rel_sub  = (float*)alloc((size_t)4096 * 512 * 4);
    float* rel_obj2 = (float*)alloc((size_t)4096 * 512 * 4);
    float* rel_sub2 = (float*)alloc((size_t)4096 * 512 * 4);

    cvt_bf16_kernel<<<2048, 256, 0, stream>>>((const float4*)feat_obj, (ushort4*)bf_obj, 2048 * 1024 / 4);
    cvt_bf16_kernel<<<4096, 256, 0, stream>>>((const float4*)feat_rel, (ushort4*)bf_rel, 4096 * 1024 / 4);
    transcvt_kernel<<<dim3(16, 32, 12), dim3(32, 8), 0, stream>>>(W_cat, Wt_cat, 1024, 512);

    const float sc1 = 0.08838834764831845f;  // 1/sqrt(128)
    const float sc2 = 0.04419417382415922f;  // 1/sqrt(512)
    const long planeW = (long)512 * 1024;
    const long planeW2 = (long)3072 * 1024;

    // ---------------- stage 1: three concat=True MHAs, h=4, d_k=128 ----------------
    struct MhaCfg { const u16* xq; const u16* xk; int Nq, Nk; float* d1; float* d2; int mask; };
    MhaCfg cfg[3] = {
        { bf_obj, bf_obj, 2048, 2048, sub_obj, obj_sub, 1 },
        { bf_obj, bf_rel, 2048, 4096, sub_rel, rel_sub, 0 },
        { bf_rel, bf_obj, 4096, 2048, rel_obj, obj_rel, 0 },
    };
    for (int m = 0; m < 3; ++m) {
        const u16* Wt = Wt_cat + (size_t)m * 4 * planeW;
        const float* bb = b_cat + m * 4 * 512;
        int Nq = cfg[m].Nq, Nk = cfg[m].Nk;
        long splane = (long)Nq * Nk;
        // projections: z=0 -> {q,k}, z=1 -> {qv,kv}
        gemm_nt<E_PROJ, 64><<<dim3(Nq / 64, 8, 2), 256, 0, stream>>>(
            cfg[m].xq, Wt, bufQV, bb, Nq, 512, 1024, 1024, 1024, 512, 0.f,
            0, 2 * planeW, (long)Nq * 512, 1024);
        gemm_nt<E_PROJ, 64><<<dim3(Nk / 64, 8, 2), 256, 0, stream>>>(
            cfg[m].xk, Wt + planeW, bufKV, bb + 512, Nk, 512, 1024, 1024, 1024, 512, 0.f,
            0, 2 * planeW, (long)Nk * 512, 1024);
        // V transposes: kv^T [512][Nk], qv^T [512][Nq]
        transpose_bf16_kernel<<<dim3(Nk / 64, 8, 1), 256, 0, stream>>>(
            bufKV + (size_t)Nk * 512, VTa, Nk, 512, 0);
        transpose_bf16_kernel<<<dim3(Nq / 64, 8, 1), 256, 0, stream>>>(
            bufQV + (size_t)Nq * 512, VTb, Nq, 512, 0);
        // scores, all 4 heads in one dispatch
        if (cfg[m].mask)
            gemm_nt<E_SCM, 128><<<dim3(Nq / 128, Nk / 128, 4), 256, 0, stream>>>(
                bufQV, bufKV, Sbuf, nullptr, Nq, Nk, 128, 512, 512, Nk, sc1, 128, 128, splane, 0);
        else
            gemm_nt<E_SC, 128><<<dim3(Nq / 128, Nk / 128, 4), 256, 0, stream>>>(
                bufQV, bufKV, Sbuf, nullptr, Nq, Nk, 128, 512, 512, Nk, sc1, 128, 128, splane, 0);
        softmax_kernel<<<dim3(Nq, 4), 256, 0, stream>>>(Sbuf, Nk, splane);
        transpose_bf16_kernel<<<dim3(Nq / 64, Nk / 64, 4), 256, 0, stream>>>(Sbuf, PTbuf, Nq, Nk, splane);
        // a1 = elu(P @ kv_h) -> d1[:, h*128:(h+1)*128]
        gemm_nt<E_ELW, 64><<<dim3(Nq / 64, 2, 4), 256, 0, stream>>>(
            Sbuf, VTa, cfg[m].d1, nullptr, Nq, 128, Nk, Nk, Nk, 512, 0.f,
            splane, 128L * Nk, 128, 0);
        // a2 = elu(P^T @ qv_h) -> d2[:, h*128:(h+1)*128]
        gemm_nt<E_ELW, 64><<<dim3(Nk / 64, 2, 4), 256, 0, stream>>>(
            PTbuf, VTb, cfg[m].d2, nullptr, Nk, 128, Nq, Nq, Nq, 512, 0.f,
            splane, 128L * Nq, 128, 0);
    }

    combine_obj_kernel<<<2048, 256, 0, stream>>>((const float4*)feat_obj, (const float4*)sub_obj,
        (const float4*)obj_sub, (const float4*)sub_rel, (const float4*)obj_rel,
        (float4*)out_obj, (ushort4*)bf_obj2);
    combine_rel1_kernel<<<4096, 256, 0, stream>>>((const float4*)feat_rel, (const float4*)rel_obj,
        (const float4*)rel_sub, (ushort4*)bf_rel2);

    // ---------------- stage 2: two concat=False MHAs, h=6, d_k=512 ----------------
    // mha0: xq=obj2 (2048), xk=rel2 (4096); need a2 = sum_h elu(P_h^T @ qv_h)
    {
        transcvt_kernel<<<dim3(96, 32, 3), dim3(32, 8), 0, stream>>>(W_out, Wt2, 1024, 3072);
        // z=0 -> q (W0,b0), z=1 -> qv (W2,b2)
        gemm_nt<E_PROJ, 128><<<dim3(16, 24, 2), 256, 0, stream>>>(
            bf_obj2, Wt2, bufQV, b_out, 2048, 3072, 1024, 1024, 1024, 3072, 0.f,
            0, 2 * planeW2, (long)2048 * 3072, 2L * 3072);
        gemm_nt<E_PROJ, 128><<<dim3(32, 24, 1), 256, 0, stream>>>(
            bf_rel2, Wt2 + planeW2, bufKV, b_out + 3072, 4096, 3072, 1024, 1024, 1024, 3072, 0.f,
            0, 0, 0, 0);
        transpose_bf16_kernel<<<dim3(32, 48, 1), 256, 0, stream>>>(
            bufQV + (size_t)2048 * 3072, VTa, 2048, 3072, 0);   // qv^T [3072][2048]
        for (int hc0 = 0; hc0 < 6; hc0 += 3) {
            gemm_nt<E_SC, 128><<<dim3(16, 32, 3), 256, 0, stream>>>(
                bufQV + hc0 * 512, bufKV + hc0 * 512, Sbuf, nullptr, 2048, 4096, 512,
                3072, 3072, 4096, sc2, 512, 512, (long)2048 * 4096, 0);
            softmax_kernel<<<dim3(2048, 3), 256, 0, stream>>>(Sbuf, 4096, (long)2048 * 4096);
            transpose_bf16_kernel<<<dim3(32, 64, 3), 256, 0, stream>>>(Sbuf, PTbuf, 2048, 4096,
                                                                       (long)2048 * 4096);
            gemm_nt<E_PART, 128><<<dim3(32, 4, 3), 256, 0, stream>>>(
                PTbuf, VTa + (size_t)hc0 * 512 * 2048, part, nullptr, 4096, 512, 2048,
                2048, 2048, 512, 0.f, (long)4096 * 2048, 512L * 2048, (long)4096 * 512, 0);
            reduce_elu4_kernel<<<2048, 256, 0, stream>>>((const float4*)part, (float4*)rel_sub2,
                4096 * 512 / 4, 3, (long)4096 * 512 / 4, hc0 > 0);
        }
    }
    // mha1: xq=rel2 (4096), xk=obj2 (2048); need a1 = sum_h elu(P_h @ kv_h)
    {
        transcvt_kernel<<<dim3(96, 32, 4), dim3(32, 8), 0, stream>>>(W_out + 4 * planeW2, Wt2, 1024, 3072);
        gemm_nt<E_PROJ, 128><<<dim3(32, 24, 1), 256, 0, stream>>>(
            bf_rel2, Wt2, bufQV, b_out + 4 * 3072, 4096, 3072, 1024, 1024, 1024, 3072, 0.f,
            0, 0, 0, 0);
        // z=0 -> k (W1,b1), z=1 -> kv (W3,b3)
        gemm_nt<E_PROJ, 128><<<dim3(16, 24, 2), 256, 0, stream>>>(
            bf_obj2, Wt2 + planeW2, bufKV, b_out + 5 * 3072, 2048, 3072, 1024, 1024, 1024, 3072, 0.f,
            0, 2 * planeW2, (long)2048 * 3072, 2L * 3072);
        transpose_bf16_kernel<<<dim3(32, 48, 1), 256, 0, stream>>>(
            bufKV + (size_t)2048 * 3072, VTa, 2048, 3072, 0);   // kv^T [3072][2048]
        for (int hc0 = 0; hc0 < 6; hc0 += 3) {
            gemm_nt<E_SC, 128><<<dim3(32, 16, 3), 256, 0, stream>>>(
                bufQV + hc0 * 512, bufKV + hc0 * 512, Sbuf, nullptr, 4096, 2048, 512,
                3072, 3072, 2048, sc2, 512, 512, (long)4096 * 2048, 0);
            softmax_kernel<<<dim3(4096, 3), 256, 0, stream>>>(Sbuf, 2048, (long)4096 * 2048);
            gemm_nt<E_PART, 128><<<dim3(32, 4, 3), 256, 0, stream>>>(
                Sbuf, VTa + (size_t)hc0 * 512 * 2048, part, nullptr, 4096, 512, 2048,
                2048, 2048, 512, 0.f, (long)4096 * 2048, 512L * 2048, (long)4096 * 512, 0);
            reduce_elu4_kernel<<<2048, 256, 0, stream>>>((const float4*)part, (float4*)rel_obj2,
                4096 * 512 / 4, 3, (long)4096 * 512 / 4, hc0 > 0);
        }
    }

    combine_rel2_kernel<<<4096, 256, 0, stream>>>((const float4*)feat_rel, (const float4*)rel_obj2,
        (const float4*)rel_sub2, (float4*)out_rel);
}

// Round 5
// 1039.224 us; speedup vs baseline: 6.6423x; 1.1354x over previous
//
#include <hip/hip_runtime.h>

typedef unsigned short u16;
typedef unsigned int u32;
typedef __attribute__((ext_vector_type(4))) float f32x4;
typedef __attribute__((ext_vector_type(8))) __bf16 bf16x8;
typedef __attribute__((ext_vector_type(8))) unsigned short u16x8;

#if defined(__has_builtin)
#if __has_builtin(__builtin_amdgcn_global_load_lds)
#define HAS_GLL 1
#endif
#endif

__device__ __forceinline__ u16 f2bf(float f) {
    u32 u = __builtin_bit_cast(u32, f);
    u += 0x7fffu + ((u >> 16) & 1u);
    return (u16)(u >> 16);
}
__device__ __forceinline__ float bf2f(u16 x) {
    return __builtin_bit_cast(float, (u32)x << 16);
}

// ---------------- elementwise conversion ----------------
__global__ __launch_bounds__(256) void cvt_bf16_kernel(const float4* __restrict__ in,
                                                       ushort4* __restrict__ out, int n4) {
    int i = blockIdx.x * 256 + threadIdx.x;
    if (i < n4) {
        float4 v = in[i];
        ushort4 o;
        o.x = f2bf(v.x); o.y = f2bf(v.y); o.z = f2bf(v.z); o.w = f2bf(v.w);
        out[i] = o;
    }
}

// transpose + convert: W [B][K][N] f32 -> Wt [B][N][K] bf16
__global__ __launch_bounds__(256) void transcvt_kernel(const float* __restrict__ W,
                                                       u16* __restrict__ Wt, int K, int N) {
    __shared__ u16 t[32][33];
    int b = blockIdx.z;
    const float* Wb = W + (size_t)b * K * N;
    u16* Wtb = Wt + (size_t)b * K * N;
    int n0 = blockIdx.x * 32, k0 = blockIdx.y * 32;
    int tx = threadIdx.x, ty = threadIdx.y;
#pragma unroll
    for (int j = 0; j < 4; ++j)
        t[ty + j * 8][tx] = f2bf(Wb[(size_t)(k0 + ty + j * 8) * N + n0 + tx]);
    __syncthreads();
#pragma unroll
    for (int j = 0; j < 4; ++j)
        Wtb[(size_t)(n0 + ty + j * 8) * K + k0 + tx] = t[tx][ty + j * 8];
}

// bf16 transpose per z-plane: in [z][R][C] -> out [z][C][R]
__global__ __launch_bounds__(256) void transpose_bf16_kernel(const u16* __restrict__ in,
                                                             u16* __restrict__ out, int R, int C,
                                                             long plane) {
    __shared__ u16 t[64][65];
    const u16* inz = in + (size_t)blockIdx.z * plane;
    u16* outz = out + (size_t)blockIdx.z * plane;
    int r0 = blockIdx.x * 64, c0 = blockIdx.y * 64;
    int tx = threadIdx.x & 15, ty = threadIdx.x >> 4;
#pragma unroll
    for (int j = 0; j < 4; ++j) {
        int r = ty + j * 16;
        ushort4 v = *reinterpret_cast<const ushort4*>(inz + (size_t)(r0 + r) * C + c0 + tx * 4);
        t[r][tx * 4 + 0] = v.x; t[r][tx * 4 + 1] = v.y;
        t[r][tx * 4 + 2] = v.z; t[r][tx * 4 + 3] = v.w;
    }
    __syncthreads();
#pragma unroll
    for (int j = 0; j < 4; ++j) {
        int c = ty + j * 16;
        ushort4 v;
        v.x = t[tx * 4 + 0][c]; v.y = t[tx * 4 + 1][c];
        v.z = t[tx * 4 + 2][c]; v.w = t[tx * 4 + 3][c];
        *reinterpret_cast<ushort4*>(outz + (size_t)(c0 + c) * R + r0 + tx * 4) = v;
    }
}

// ---------------- rd[z][row] = 1 / sum_col expS[z][row][col] ----------------
__global__ __launch_bounds__(256) void rowsum_inv_kernel(const u16* __restrict__ S,
                                                         float* __restrict__ rd, int N,
                                                         long plane, int R) {
    int row = blockIdx.x, z = blockIdx.y;
    const u16* s = S + (size_t)z * plane + (size_t)row * N;
    int tid = threadIdx.x, lane = tid & 63, wid = tid >> 6;
    int cnt = N >> 11;
    __shared__ float red[4];
    float sum = 0.f;
    for (int c = 0; c < cnt; ++c) {
        u16x8 x = *reinterpret_cast<const u16x8*>(s + c * 2048 + tid * 8);
#pragma unroll
        for (int j = 0; j < 8; ++j) sum += bf2f(x[j]);
    }
#pragma unroll
    for (int off = 32; off; off >>= 1) sum += __shfl_down(sum, off);
    if (lane == 0) red[wid] = sum;
    __syncthreads();
    if (tid == 0) rd[(size_t)z * R + row] = 1.f / (red[0] + red[1] + red[2] + red[3]);
}

// ---------------- column-sum partials: partial[z][rb][col] = sum_{r in chunk} S[z][r][col] ----------------
__global__ __launch_bounds__(256) void colsum_part_kernel(const u16* __restrict__ S,
                                                          float* __restrict__ partial,
                                                          int R, int C, int rchunk, int nrb) {
    int col = blockIdx.x * 256 + threadIdx.x;
    int rb = blockIdx.y, z = blockIdx.z;
    const u16* s = S + (size_t)z * R * C + (size_t)rb * rchunk * C + col;
    float sum = 0.f;
    for (int r = 0; r < rchunk; ++r) sum += bf2f(s[(size_t)r * C]);
    partial[((size_t)z * nrb + rb) * C + col] = sum;
}

__global__ __launch_bounds__(256) void colsum_fin_kernel(const float* __restrict__ partial,
                                                         float* __restrict__ rd, int C, int nrb) {
    int col = blockIdx.x * 256 + threadIdx.x;
    int z = blockIdx.y;
    float sum = 0.f;
    for (int rb = 0; rb < nrb; ++rb) sum += partial[((size_t)z * nrb + rb) * C + col];
    rd[(size_t)z * C + col] = 1.f / sum;
}

// ---------------- scale rows of a [R][C] bf16 matrix by rd[(r>>lg)·C + c] ----------------
__global__ __launch_bounds__(256) void scale_rows_kernel(const u16* __restrict__ in,
                                                         u16* __restrict__ out,
                                                         const float* __restrict__ rd,
                                                         int C, int lgdk) {
    int i = (blockIdx.x * 256 + threadIdx.x) * 8;
    int r = i / C, c = i % C;
    const float* rdp = rd + ((size_t)(r >> lgdk)) * C + c;
    u16x8 x = *reinterpret_cast<const u16x8*>(in + i);
    u16x8 o;
#pragma unroll
    for (int j = 0; j < 8; ++j) o[j] = f2bf(bf2f(x[j]) * rdp[j]);
    *reinterpret_cast<u16x8*>(out + i) = o;
}

// ---------------- GEMM: C = A (M,K) * B^T (N,K), row-major, 2-phase prefetch ----------------
// z-batched: A += z*sAz, B += z*sBz, C elem offset += z*sCz, bias += z*sBias, rs += z*sRs.
enum { E_PROJ = 0, E_EXP, E_EXPM, E_ELW, E_ELR, E_PART, E_PARTR };

template <int EPI, int BM>
__global__ __launch_bounds__(256) void gemm_nt(const u16* __restrict__ A, const u16* __restrict__ B,
                                               void* __restrict__ Cv, const float* __restrict__ bias,
                                               const float* __restrict__ rs,
                                               int M, int N, int K, int lda, int ldb, int ldc,
                                               float scale, long sAz, long sBz, long sCz,
                                               long sBias, long sRs) {
    constexpr int MF = BM / 32;               // 16x16 frags per wave dim
    constexpr int ITERS = BM * 32 / (256 * 8);
    __shared__ __align__(16) u16 As[2][BM * 32];
    __shared__ __align__(16) u16 Bs[2][BM * 32];
    const int tid = threadIdx.x;
    const int lane = tid & 63;
    const int wid = tid >> 6;
    const int wr = (wid >> 1) * (BM / 2);
    const int wc = (wid & 1) * (BM / 2);
    const int row0 = blockIdx.x * BM;
    const int col0 = blockIdx.y * BM;
    const long zo = blockIdx.z;
    const u16* Az = A + zo * sAz;
    const u16* Bz = B + zo * sBz;
    const long zoff = zo * sCz;
    const float* biasz = bias ? bias + zo * sBias : nullptr;
    const float* rsz = rs ? rs + zo * sRs : nullptr;
    f32x4 acc[MF][MF] = {};

    auto stage = [&](int buf, int k0) {
#pragma unroll
        for (int i = 0; i < ITERS; ++i) {
            int c = tid + i * 256;
            int r = c >> 2;
            int lch = (c & 3) ^ ((r >> 1) & 3);   // logical k-chunk at this physical slot
            const u16* sa = Az + (size_t)(row0 + r) * lda + k0 + lch * 8;
            const u16* sb = Bz + (size_t)(col0 + r) * ldb + k0 + lch * 8;
#ifdef HAS_GLL
            __builtin_amdgcn_global_load_lds(
                (const __attribute__((address_space(1))) void*)sa,
                (__attribute__((address_space(3))) void*)(&As[buf][c * 8]), 16, 0, 0);
            __builtin_amdgcn_global_load_lds(
                (const __attribute__((address_space(1))) void*)sb,
                (__attribute__((address_space(3))) void*)(&Bs[buf][c * 8]), 16, 0, 0);
#else
            *reinterpret_cast<uint4*>(&As[buf][c * 8]) = *reinterpret_cast<const uint4*>(sa);
            *reinterpret_cast<uint4*>(&Bs[buf][c * 8]) = *reinterpret_cast<const uint4*>(sb);
#endif
        }
    };

    stage(0, 0);
    __syncthreads();
    int cur = 0;
    for (int k0 = 0; k0 < K; k0 += 32) {
        if (k0 + 32 < K) stage(cur ^ 1, k0 + 32);
        bf16x8 af[MF], bv[MF];
#pragma unroll
        for (int m = 0; m < MF; ++m) {
            int rr = wr + m * 16 + (lane & 15);
            int p = (lane >> 4) ^ ((rr >> 1) & 3);
            af[m] = *reinterpret_cast<const bf16x8*>(&As[cur][rr * 32 + p * 8]);
        }
#pragma unroll
        for (int n = 0; n < MF; ++n) {
            int rr = wc + n * 16 + (lane & 15);
            int p = (lane >> 4) ^ ((rr >> 1) & 3);
            bv[n] = *reinterpret_cast<const bf16x8*>(&Bs[cur][rr * 32 + p * 8]);
        }
#pragma unroll
        for (int m = 0; m < MF; ++m)
#pragma unroll
            for (int n = 0; n < MF; ++n)
                acc[m][n] = __builtin_amdgcn_mfma_f32_16x16x32_bf16(af[m], bv[n], acc[m][n], 0, 0, 0);
        __syncthreads();          // drains prefetch + protects buffer swap
        cur ^= 1;
    }

#pragma unroll
    for (int m = 0; m < MF; ++m) {
#pragma unroll
        for (int n = 0; n < MF; ++n) {
#pragma unroll
            for (int j = 0; j < 4; ++j) {
                int row = row0 + wr + m * 16 + ((lane >> 4) << 2) + j;
                int col = col0 + wc + n * 16 + (lane & 15);
                float v = acc[m][n][j];
                if (EPI == E_PROJ) {
                    v += biasz[col];
                    reinterpret_cast<u16*>(Cv)[zoff + (size_t)row * ldc + col] = f2bf(v);
                } else if (EPI == E_EXP || EPI == E_EXPM) {
                    v = __expf(v * scale);
                    if (EPI == E_EXPM && row == col) v = 0.f;
                    reinterpret_cast<u16*>(Cv)[zoff + (size_t)row * ldc + col] = f2bf(v);
                } else if (EPI == E_ELW || EPI == E_ELR) {
                    if (EPI == E_ELR) v *= rsz[row];
                    v = v > 0.f ? v : (__expf(v) - 1.f);
                    reinterpret_cast<float*>(Cv)[zoff + (size_t)row * ldc + col] = v;
                } else {  // E_PART / E_PARTR: bf16 partial per z-plane (pre-ELU)
                    if (EPI == E_PARTR) v *= rsz[row];
                    reinterpret_cast<u16*>(Cv)[zoff + (size_t)row * ldc + col] = f2bf(v);
                }
            }
        }
    }
}

// ---------------- reduce: out = sum_z elu(part[z]); part bf16, out f32 ----------------
__global__ __launch_bounds__(256) void reduce_elu8_kernel(const u16* __restrict__ part,
                                                          float* __restrict__ out, int MN8, int Z,
                                                          long plane) {
    int i = blockIdx.x * 256 + threadIdx.x;
    if (i >= MN8) return;
    float s[8] = {};
    for (int z = 0; z < Z; ++z) {
        u16x8 p = *reinterpret_cast<const u16x8*>(part + (size_t)z * plane + (size_t)i * 8);
#pragma unroll
        for (int j = 0; j < 8; ++j) {
            float v = bf2f(p[j]);
            s[j] += v > 0.f ? v : (__expf(v) - 1.f);
        }
    }
    float4* o = reinterpret_cast<float4*>(out + (size_t)i * 8);
    o[0] = float4{s[0], s[1], s[2], s[3]};
    o[1] = float4{s[4], s[5], s[6], s[7]};
}

// ---------------- combines (float4) ----------------
__global__ __launch_bounds__(256) void combine_obj_kernel(const float4* __restrict__ feat,
        const float4* __restrict__ a, const float4* __restrict__ b,
        const float4* __restrict__ c, const float4* __restrict__ d,
        float4* __restrict__ out, ushort4* __restrict__ outbf) {
    int i = blockIdx.x * 256 + threadIdx.x;
    int r = i >> 8, c4 = i & 255;
    size_t half = (size_t)r * 128 + (c4 & 127);
    float4 t1 = (c4 < 128) ? a[half] : b[half];
    float4 t2 = (c4 < 128) ? c[half] : d[half];
    float4 f = feat[i];
    float4 o;
    o.x = (f.x + t1.x + t2.x) * (1.f / 3.f);
    o.y = (f.y + t1.y + t2.y) * (1.f / 3.f);
    o.z = (f.z + t1.z + t2.z) * (1.f / 3.f);
    o.w = (f.w + t1.w + t2.w) * (1.f / 3.f);
    out[i] = o;
    ushort4 ob; ob.x = f2bf(o.x); ob.y = f2bf(o.y); ob.z = f2bf(o.z); ob.w = f2bf(o.w);
    outbf[i] = ob;
}

__global__ __launch_bounds__(256) void combine_rel1_kernel(const float4* __restrict__ feat,
        const float4* __restrict__ a, const float4* __restrict__ b, ushort4* __restrict__ outbf) {
    int i = blockIdx.x * 256 + threadIdx.x;
    int r = i >> 8, c4 = i & 255;
    size_t half = (size_t)r * 128 + (c4 & 127);
    float4 t = (c4 < 128) ? a[half] : b[half];
    float4 f = feat[i];
    ushort4 ob;
    ob.x = f2bf((f.x + t.x) * 0.5f); ob.y = f2bf((f.y + t.y) * 0.5f);
    ob.z = f2bf((f.z + t.z) * 0.5f); ob.w = f2bf((f.w + t.w) * 0.5f);
    outbf[i] = ob;
}

__global__ __launch_bounds__(256) void combine_rel2_kernel(const float4* __restrict__ feat,
        const float4* __restrict__ a, const float4* __restrict__ b, float4* __restrict__ out) {
    int i = blockIdx.x * 256 + threadIdx.x;
    int r = i >> 8, c4 = i & 255;
    size_t half = (size_t)r * 128 + (c4 & 127);
    float4 t = (c4 < 128) ? a[half] : b[half];
    float4 f = feat[i];
    float4 o;
    o.x = (f.x + t.x) * 0.5f; o.y = (f.y + t.y) * 0.5f;
    o.z = (f.z + t.z) * 0.5f; o.w = (f.w + t.w) * 0.5f;
    out[i] = o;
}

extern "C" void kernel_launch(void* const* d_in, const int* in_sizes, int n_in,
                              void* d_out, int out_size, void* d_ws, size_t ws_size,
                              hipStream_t stream) {
    (void)in_sizes; (void)n_in; (void)out_size; (void)ws_size;
    const float* feat_obj = (const float*)d_in[0];
    const float* feat_rel = (const float*)d_in[1];
    const float* W_cat = (const float*)d_in[2];
    const float* b_cat = (const float*)d_in[3];
    const float* W_out = (const float*)d_in[4];
    const float* b_out = (const float*)d_in[5];
    float* out_obj = (float*)d_out;
    float* out_rel = (float*)d_out + (size_t)2048 * 1024;

    char* w = (char*)d_ws;
    auto alloc = [&](size_t bytes) { void* p = (void*)w; w += (bytes + 255) & ~(size_t)255; return p; };
    u16* bf_obj  = (u16*)alloc((size_t)2048 * 1024 * 2);
    u16* bf_rel  = (u16*)alloc((size_t)4096 * 1024 * 2);
    u16* bf_obj2 = (u16*)alloc((size_t)2048 * 1024 * 2);
    u16* bf_rel2 = (u16*)alloc((size_t)4096 * 1024 * 2);
    u16* Wt_cat  = (u16*)alloc((size_t)12 * 512 * 1024 * 2);     // 12 MiB
    u16* Wt2     = (u16*)alloc((size_t)4 * 3072 * 1024 * 2);     // 24 MiB
    u16* bufQV   = (u16*)alloc((size_t)2 * 2048 * 3072 * 2);     // 24 MiB
    u16* bufKV   = (u16*)alloc((size_t)2 * 2048 * 3072 * 2);     // 24 MiB
    u16* VTa     = (u16*)alloc((size_t)3072 * 2048 * 2);         // 12 MiB
    u16* VTb     = (u16*)alloc((size_t)512 * 4096 * 2);          // 4 MiB
    u16* VTs     = (u16*)alloc((size_t)3072 * 2048 * 2);         // 12 MiB (scaled V^T)
    u16* Sbuf    = (u16*)alloc((size_t)6 * 4096 * 2048 * 2);     // 96 MiB (expS planes)
    u16* PTbuf   = (u16*)alloc((size_t)4 * 2048 * 4096 * 2);     // 64 MiB (stage1 expS^T)
    u16* part    = (u16*)alloc((size_t)6 * 4096 * 512 * 2);      // 24 MiB bf16 partials
    float* rdH   = (float*)alloc((size_t)4 * 4096 * 4);
    float* rdQ   = (float*)alloc((size_t)6 * 2048 * 4);
    float* rdM   = (float*)alloc((size_t)6 * 4096 * 4);
    float* csP   = (float*)alloc((size_t)6 * 16 * 2048 * 4);     // colsum partials
    float* sub_obj  = (float*)alloc((size_t)2048 * 512 * 4);
    float* obj_sub  = (float*)alloc((size_t)2048 * 512 * 4);
    float* sub_rel  = (float*)alloc((size_t)2048 * 512 * 4);
    float* obj_rel  = (float*)alloc((size_t)2048 * 512 * 4);
    float* rel_obj  = (float*)alloc((size_t)4096 * 512 * 4);
    float* rel_sub  = (float*)alloc((size_t)4096 * 512 * 4);
    float* rel_obj2 = (float*)alloc((size_t)4096 * 512 * 4);
    float* rel_sub2 = (float*)alloc((size_t)4096 * 512 * 4);

    cvt_bf16_kernel<<<2048, 256, 0, stream>>>((const float4*)feat_obj, (ushort4*)bf_obj, 2048 * 1024 / 4);
    cvt_bf16_kernel<<<4096, 256, 0, stream>>>((const float4*)feat_rel, (ushort4*)bf_rel, 4096 * 1024 / 4);
    transcvt_kernel<<<dim3(16, 32, 12), dim3(32, 8), 0, stream>>>(W_cat, Wt_cat, 1024, 512);

    const float sc1 = 0.08838834764831845f;  // 1/sqrt(128)
    const float sc2 = 0.04419417382415922f;  // 1/sqrt(512)
    const long planeW = (long)512 * 1024;
    const long planeW2 = (long)3072 * 1024;
    const long NIL = 0;

    // ---------------- stage 1: three concat=True MHAs, h=4, d_k=128 ----------------
    struct MhaCfg { const u16* xq; const u16* xk; int Nq, Nk; float* d1; float* d2; int mask; };
    MhaCfg cfg[3] = {
        { bf_obj, bf_obj, 2048, 2048, sub_obj, obj_sub, 1 },
        { bf_obj, bf_rel, 2048, 4096, sub_rel, rel_sub, 0 },
        { bf_rel, bf_obj, 4096, 2048, rel_obj, obj_rel, 0 },
    };
    for (int m = 0; m < 3; ++m) {
        const u16* Wt = Wt_cat + (size_t)m * 4 * planeW;
        const float* bb = b_cat + m * 4 * 512;
        int Nq = cfg[m].Nq, Nk = cfg[m].Nk;
        long splane = (long)Nq * Nk;
        // projections: z=0 -> {q,k}, z=1 -> {qv,kv}
        gemm_nt<E_PROJ, 64><<<dim3(Nq / 64, 8, 2), 256, 0, stream>>>(
            cfg[m].xq, Wt, bufQV, bb, nullptr, Nq, 512, 1024, 1024, 1024, 512, 0.f,
            0, 2 * planeW, (long)Nq * 512, 1024, NIL);
        gemm_nt<E_PROJ, 64><<<dim3(Nk / 64, 8, 2), 256, 0, stream>>>(
            cfg[m].xk, Wt + planeW, bufKV, bb + 512, nullptr, Nk, 512, 1024, 1024, 1024, 512, 0.f,
            0, 2 * planeW, (long)Nk * 512, 1024, NIL);
        // V transposes: kv^T [512][Nk], qv^T [512][Nq]
        transpose_bf16_kernel<<<dim3(Nk / 64, 8, 1), 256, 0, stream>>>(
            bufKV + (size_t)Nk * 512, VTa, Nk, 512, 0);
        transpose_bf16_kernel<<<dim3(Nq / 64, 8, 1), 256, 0, stream>>>(
            bufQV + (size_t)Nq * 512, VTb, Nq, 512, 0);
        // expS = exp(scale * Q K^T), 4 heads; masked variant zeroes diagonal
        if (cfg[m].mask)
            gemm_nt<E_EXPM, 128><<<dim3(Nq / 128, Nk / 128, 4), 256, 0, stream>>>(
                bufQV, bufKV, Sbuf, nullptr, nullptr, Nq, Nk, 128, 512, 512, Nk, sc1,
                128, 128, splane, NIL, NIL);
        else
            gemm_nt<E_EXP, 128><<<dim3(Nq / 128, Nk / 128, 4), 256, 0, stream>>>(
                bufQV, bufKV, Sbuf, nullptr, nullptr, Nq, Nk, 128, 512, 512, Nk, sc1,
                128, 128, splane, NIL, NIL);
        // rdH[h][q] = 1/rowsum
        rowsum_inv_kernel<<<dim3(Nq, 4), 256, 0, stream>>>(Sbuf, rdH, Nk, splane, Nq);
        // expS^T for a2
        transpose_bf16_kernel<<<dim3(Nq / 64, Nk / 64, 4), 256, 0, stream>>>(Sbuf, PTbuf, Nq, Nk, splane);
        // a1 = elu(diag(rd) expS kv^T) -> d1[:, h*128:(h+1)*128]
        gemm_nt<E_ELR, 64><<<dim3(Nq / 64, 2, 4), 256, 0, stream>>>(
            Sbuf, VTa, cfg[m].d1, nullptr, rdH, Nq, 128, Nk, Nk, Nk, 512, 0.f,
            splane, 128L * Nk, 128, NIL, Nq);
        // VTs = qv^T with columns q scaled by rdH[h][q]
        scale_rows_kernel<<<512 * Nq / 2048, 256, 0, stream>>>(VTb, VTs, rdH, Nq, 7);
        // a2 = elu(expS^T qv'^T) -> d2[:, h*128:(h+1)*128]
        gemm_nt<E_ELW, 64><<<dim3(Nk / 64, 2, 4), 256, 0, stream>>>(
            PTbuf, VTs, cfg[m].d2, nullptr, nullptr, Nk, 128, Nq, Nq, Nq, 512, 0.f,
            splane, 128L * Nq, 128, NIL, NIL);
    }

    combine_obj_kernel<<<2048, 256, 0, stream>>>((const float4*)feat_obj, (const float4*)sub_obj,
        (const float4*)obj_sub, (const float4*)sub_rel, (const float4*)obj_rel,
        (float4*)out_obj, (ushort4*)bf_obj2);
    combine_rel1_kernel<<<4096, 256, 0, stream>>>((const float4*)feat_rel, (const float4*)rel_obj,
        (const float4*)rel_sub, (ushort4*)bf_rel2);

    const long spl2 = (long)4096 * 2048;   // stage-2 score plane
    const long vpl2 = (long)4096 * 512;    // stage-2 part plane

    // ---------------- stage 2 mha0: xq=obj2 (2048), xk=rel2 (4096); a2 only ----------------
    {
        transcvt_kernel<<<dim3(96, 32, 3), dim3(32, 8), 0, stream>>>(W_out, Wt2, 1024, 3072);
        // z=0 -> q (W0,b0), z=1 -> qv (W2,b2)
        gemm_nt<E_PROJ, 128><<<dim3(16, 24, 2), 256, 0, stream>>>(
            bf_obj2, Wt2, bufQV, b_out, nullptr, 2048, 3072, 1024, 1024, 1024, 3072, 0.f,
            0, 2 * planeW2, (long)2048 * 3072, 2L * 3072, NIL);
        gemm_nt<E_PROJ, 128><<<dim3(32, 24, 1), 256, 0, stream>>>(
            bf_rel2, Wt2 + planeW2, bufKV, b_out + 3072, nullptr, 4096, 3072, 1024,
            1024, 1024, 3072, 0.f, 0, 0, 0, NIL, NIL);
        transpose_bf16_kernel<<<dim3(32, 48, 1), 256, 0, stream>>>(
            bufQV + (size_t)2048 * 3072, VTa, 2048, 3072, 0);   // qv^T [3072][2048]
        // swapped scores: expS'[h][m_key][q] = exp(sc2 * K Q^T), all 6 heads
        gemm_nt<E_EXP, 128><<<dim3(32, 16, 6), 256, 0, stream>>>(
            bufKV, bufQV, Sbuf, nullptr, nullptr, 4096, 2048, 512, 3072, 3072, 2048, sc2,
            512, 512, spl2, NIL, NIL);
        // denominators: rdQ[h][q] = 1/colsum(expS'[h])
        colsum_part_kernel<<<dim3(8, 16, 6), 256, 0, stream>>>(Sbuf, csP, 4096, 2048, 256, 16);
        colsum_fin_kernel<<<dim3(8, 6), 256, 0, stream>>>(csP, rdQ, 2048, 16);
        // VTs = qv^T with columns q scaled by rdQ[h][q] (dk=512 rows/head)
        scale_rows_kernel<<<3072 * 2048 / 2048, 256, 0, stream>>>(VTa, VTs, rdQ, 2048, 9);
        // part[h] = expS'[h] @ (scaled qv^T)[h]
        gemm_nt<E_PART, 128><<<dim3(32, 4, 6), 256, 0, stream>>>(
            Sbuf, VTs, part, nullptr, nullptr, 4096, 512, 2048, 2048, 2048, 512, 0.f,
            spl2, 512L * 2048, vpl2, NIL, NIL);
        reduce_elu8_kernel<<<vpl2 / 8 / 256, 256, 0, stream>>>(part, rel_sub2, vpl2 / 8, 6, vpl2);
    }
    // ---------------- stage 2 mha1: xq=rel2 (4096), xk=obj2 (2048); a1 only ----------------
    {
        transcvt_kernel<<<dim3(96, 32, 4), dim3(32, 8), 0, stream>>>(W_out + 4 * planeW2, Wt2, 1024, 3072);
        gemm_nt<E_PROJ, 128><<<dim3(32, 24, 1), 256, 0, stream>>>(
            bf_rel2, Wt2, bufQV, b_out + 4 * 3072, nullptr, 4096, 3072, 1024,
            1024, 1024, 3072, 0.f, 0, 0, 0, NIL, NIL);
        // z=0 -> k (W1,b1), z=1 -> kv (W3,b3)
        gemm_nt<E_PROJ, 128><<<dim3(16, 24, 2), 256, 0, stream>>>(
            bf_obj2, Wt2 + planeW2, bufKV, b_out + 5 * 3072, nullptr, 2048, 3072, 1024,
            1024, 1024, 3072, 0.f, 0, 2 * planeW2, (long)2048 * 3072, 2L * 3072, NIL);
        transpose_bf16_kernel<<<dim3(32, 48, 1), 256, 0, stream>>>(
            bufKV + (size_t)2048 * 3072, VTa, 2048, 3072, 0);   // kv^T [3072][2048]
        // scores: expS[h][q_rel][k_obj], all 6 heads
        gemm_nt<E_EXP, 128><<<dim3(32, 16, 6), 256, 0, stream>>>(
            bufQV, bufKV, Sbuf, nullptr, nullptr, 4096, 2048, 512, 3072, 3072, 2048, sc2,
            512, 512, spl2, NIL, NIL);
        // rdM[h][row] = 1/rowsum
        rowsum_inv_kernel<<<dim3(4096, 6), 256, 0, stream>>>(Sbuf, rdM, 2048, spl2, 4096);
        // part[h] = diag(rdM) expS[h] @ kv^T[h]
        gemm_nt<E_PARTR, 128><<<dim3(32, 4, 6), 256, 0, stream>>>(
            Sbuf, VTa, part, nullptr, rdM, 4096, 512, 2048, 2048, 2048, 512, 0.f,
            spl2, 512L * 2048, vpl2, NIL, 4096);
        reduce_elu8_kernel<<<vpl2 / 8 / 256, 256, 0, stream>>>(part, rel_obj2, vpl2 / 8, 6, vpl2);
    }

    combine_rel2_kernel<<<4096, 256, 0, stream>>>((const float4*)feat_rel, (const float4*)rel_obj2,
        (const float4*)rel_sub2, (float4*)out_rel);
}